// Round 1
// baseline (1080.187 us; speedup 1.0000x reference)
//
#include <hip/hip_runtime.h>
#include <hip/hip_bf16.h>

// Problem constants (from reference setup_inputs)
#define BB 16
#define CC 2048
#define HWW 1024
#define DD 256
// 1/sqrt(1 + 1e-5)
#define BN_RSQRT 0.9999950000374997f

// ---------------------------------------------------------------------------
// Transpose: in [B][C][HW] -> out [B][HW][C]   (out = xv flat; also = xv_r)
// ---------------------------------------------------------------------------
__global__ __launch_bounds__(256) void transpose_k(const float* __restrict__ in,
                                                   float* __restrict__ out) {
    __shared__ float tile[32][33];
    int b  = blockIdx.z;
    int h0 = blockIdx.x * 32;
    int c0 = blockIdx.y * 32;
    const float* inb  = in  + (long long)b * CC * HWW;
    float*       outb = out + (long long)b * CC * HWW;
    int tx = threadIdx.x;       // 32
    int ty = threadIdx.y;       // 8
    for (int i = ty; i < 32; i += 8)
        tile[i][tx] = inb[(long long)(c0 + i) * HWW + h0 + tx];
    __syncthreads();
    for (int i = ty; i < 32; i += 8)
        outb[(long long)(h0 + i) * CC + c0 + tx] = tile[tx][i];
}

// ---------------------------------------------------------------------------
// Generic tiled fp32 GEMM.
// LAYOUT: 0 = NT  (A[m][k] lda, B[n][k] ldb)
//         1 = NN  (A[m][k] lda, B[k][n] ldb)
//         2 = TN  (A[k][m] lda, B[k][n] ldb)
// EPI:    0 = plain store, 1 = relu(scale[m]*x + bias[m])
// ---------------------------------------------------------------------------
template <int BM, int BN, int BK, int TM, int TN, int LAYOUT, int EPI>
__global__ __launch_bounds__(256) void gemm_k(
    const float* __restrict__ A, long long aBatch, int lda,
    const float* __restrict__ Bp, long long bBatch, int ldb,
    float* __restrict__ Cp, long long cBatch, int ldc,
    int M, int N, int K,
    const float* __restrict__ gp, const float* __restrict__ biasp)
{
    constexpr int THREADS = (BM / TM) * (BN / TN);  // 256
    __shared__ float As[BK][BM + 4];
    __shared__ float Bs[BK][BN + 4];

    int b = blockIdx.z;
    const float* Ab = A  + (long long)b * aBatch;
    const float* Bb = Bp + (long long)b * bBatch;
    float*       Cb = Cp + (long long)b * cBatch;

    int n0 = blockIdx.x * BN;
    int m0 = blockIdx.y * BM;
    int t  = threadIdx.x;
    int tx = t % (BN / TN);
    int ty = t / (BN / TN);

    float acc[TM][TN] = {};

    for (int k0 = 0; k0 < K; k0 += BK) {
        // ---- load A tile ----
        if (LAYOUT == 2) {  // A[k][m], contiguous in m
            constexpr int V = (BK * BM / 4) / THREADS;
            #pragma unroll
            for (int i = 0; i < V; ++i) {
                int idx = t + i * THREADS;           // over BK x (BM/4)
                int r = idx / (BM / 4), c4 = idx % (BM / 4);
                float4 v = *(const float4*)&Ab[(long long)(k0 + r) * lda + m0 + c4 * 4];
                *(float4*)&As[r][c4 * 4] = v;
            }
        } else {            // A[m][k], contiguous in k
            constexpr int V = (BM * BK / 4) / THREADS;
            #pragma unroll
            for (int i = 0; i < V; ++i) {
                int idx = t + i * THREADS;           // over BM x (BK/4)
                int r = idx / (BK / 4), c4 = idx % (BK / 4);
                float4 v = *(const float4*)&Ab[(long long)(m0 + r) * lda + k0 + c4 * 4];
                As[c4 * 4 + 0][r] = v.x;
                As[c4 * 4 + 1][r] = v.y;
                As[c4 * 4 + 2][r] = v.z;
                As[c4 * 4 + 3][r] = v.w;
            }
        }
        // ---- load B tile ----
        if (LAYOUT == 0) {  // B[n][k], contiguous in k
            constexpr int V = (BN * BK / 4) / THREADS;
            #pragma unroll
            for (int i = 0; i < V; ++i) {
                int idx = t + i * THREADS;
                int r = idx / (BK / 4), c4 = idx % (BK / 4);
                float4 v = *(const float4*)&Bb[(long long)(n0 + r) * ldb + k0 + c4 * 4];
                Bs[c4 * 4 + 0][r] = v.x;
                Bs[c4 * 4 + 1][r] = v.y;
                Bs[c4 * 4 + 2][r] = v.z;
                Bs[c4 * 4 + 3][r] = v.w;
            }
        } else {            // B[k][n], contiguous in n
            constexpr int V = (BK * BN / 4) / THREADS;
            #pragma unroll
            for (int i = 0; i < V; ++i) {
                int idx = t + i * THREADS;
                int r = idx / (BN / 4), c4 = idx % (BN / 4);
                float4 v = *(const float4*)&Bb[(long long)(k0 + r) * ldb + n0 + c4 * 4];
                *(float4*)&Bs[r][c4 * 4] = v;
            }
        }
        __syncthreads();

        #pragma unroll
        for (int k = 0; k < BK; ++k) {
            float aR[TM], bR[TN];
            #pragma unroll
            for (int i = 0; i < TM; ++i) aR[i] = As[k][ty * TM + i];
            #pragma unroll
            for (int j = 0; j < TN; ++j) bR[j] = Bs[k][tx * TN + j];
            #pragma unroll
            for (int i = 0; i < TM; ++i)
                #pragma unroll
                for (int j = 0; j < TN; ++j)
                    acc[i][j] = fmaf(aR[i], bR[j], acc[i][j]);
        }
        __syncthreads();
    }

    // ---- epilogue ----
    #pragma unroll
    for (int i = 0; i < TM; ++i) {
        int m = m0 + ty * TM + i;
        float sc = 1.0f, bi = 0.0f;
        if (EPI == 1) { sc = gp[m] * BN_RSQRT; bi = biasp[m]; }
        #pragma unroll
        for (int j0 = 0; j0 < TN; j0 += 4) {
            float4 v;
            v.x = acc[i][j0 + 0];
            v.y = acc[i][j0 + 1];
            v.z = acc[i][j0 + 2];
            v.w = acc[i][j0 + 3];
            if (EPI == 1) {
                v.x = fmaxf(fmaf(v.x, sc, bi), 0.0f);
                v.y = fmaxf(fmaf(v.y, sc, bi), 0.0f);
                v.z = fmaxf(fmaf(v.z, sc, bi), 0.0f);
                v.w = fmaxf(fmaf(v.w, sc, bi), 0.0f);
            }
            *(float4*)&Cb[(long long)m * ldc + n0 + tx * TN + j0] = v;
        }
    }
}

// ---------------------------------------------------------------------------
// Row L2-norm in place: Y [B][D][C], normalize over C
// ---------------------------------------------------------------------------
__global__ __launch_bounds__(256) void rownorm_k(float* __restrict__ Y) {
    int d = blockIdx.x, b = blockIdx.y;
    float* row = Y + ((long long)b * DD + d) * CC;
    int t = threadIdx.x;
    float s = 0.0f;
    for (int i = t; i < CC / 4; i += 256) {
        float4 v = ((const float4*)row)[i];
        s += v.x * v.x + v.y * v.y + v.z * v.z + v.w * v.w;
    }
    for (int off = 32; off > 0; off >>= 1) s += __shfl_down(s, off, 64);
    __shared__ float ws[4];
    __shared__ float ivs;
    int lane = t & 63, w = t >> 6;
    if (lane == 0) ws[w] = s;
    __syncthreads();
    if (t == 0) ivs = 1.0f / fmaxf(sqrtf(ws[0] + ws[1] + ws[2] + ws[3]), 1e-12f);
    __syncthreads();
    float iv = ivs;
    for (int i = t; i < CC / 4; i += 256) {
        float4 v = ((const float4*)row)[i];
        v.x *= iv; v.y *= iv; v.z *= iv; v.w *= iv;
        ((float4*)row)[i] = v;
    }
}

// ---------------------------------------------------------------------------
// Column L2-norm in place: Y [B][D][C], normalize over D
// ---------------------------------------------------------------------------
__global__ __launch_bounds__(256) void colnorm_k(float* __restrict__ Y) {
    int b = blockIdx.y;
    int c = blockIdx.x * 256 + threadIdx.x;
    float* base = Y + (long long)b * DD * CC + c;
    float s = 0.0f;
    for (int d = 0; d < DD; ++d) { float v = base[(long long)d * CC]; s += v * v; }
    float iv = 1.0f / fmaxf(sqrtf(s), 1e-12f);
    for (int d = 0; d < DD; ++d) base[(long long)d * CC] *= iv;
}

// ---------------------------------------------------------------------------
// rs[b,d] = 1/max(sqrt(G[b][d][d]), 1e-12)   (||latent_row||)
// ---------------------------------------------------------------------------
__global__ __launch_bounds__(256) void latnorm_k(const float* __restrict__ G,
                                                 float* __restrict__ rs) {
    int i = blockIdx.x * 256 + threadIdx.x;  // over B*D
    int b = i >> 8, d = i & 255;
    float v = G[((long long)b * DD + d) * DD + d];
    rs[i] = 1.0f / fmaxf(sqrtf(v), 1e-12f);
}

// ---------------------------------------------------------------------------
// Row softmax of logits G[d,e]*rs[d]*rs[e], in place over G. One block per row.
// ---------------------------------------------------------------------------
__global__ __launch_bounds__(256) void softmax_k(float* __restrict__ G,
                                                 const float* __restrict__ rs) {
    int d = blockIdx.x, b = blockIdx.y;
    float* row = G + ((long long)b * DD + d) * DD;
    const float* rsb = rs + (long long)b * DD;
    int t = threadIdx.x;  // e
    float l = row[t] * rsb[d] * rsb[t];

    float m = l;
    for (int off = 32; off > 0; off >>= 1) m = fmaxf(m, __shfl_down(m, off, 64));
    __shared__ float ws[4];
    __shared__ float bm, bs;
    int lane = t & 63, w = t >> 6;
    if (lane == 0) ws[w] = m;
    __syncthreads();
    if (t == 0) bm = fmaxf(fmaxf(ws[0], ws[1]), fmaxf(ws[2], ws[3]));
    __syncthreads();
    float e = expf(l - bm);
    float s = e;
    for (int off = 32; off > 0; off >>= 1) s += __shfl_down(s, off, 64);
    if (lane == 0) ws[w] = s;
    __syncthreads();
    if (t == 0) bs = ws[0] + ws[1] + ws[2] + ws[3];
    __syncthreads();
    row[t] = e / bs;
}

// ---------------------------------------------------------------------------
extern "C" void kernel_launch(void* const* d_in, const int* in_sizes, int n_in,
                              void* d_out, int out_size, void* d_ws, size_t ws_size,
                              hipStream_t stream) {
    const float* v2l   = (const float*)d_in[0];
    const float* l2v   = (const float*)d_in[1];
    const float* w_v2l = (const float*)d_in[2];
    const float* g_v2l = (const float*)d_in[3];
    const float* b_v2l = (const float*)d_in[4];
    const float* w_l2v = (const float*)d_in[5];
    const float* g_l2v = (const float*)d_in[6];
    const float* b_l2v = (const float*)d_in[7];
    float* out = (float*)d_out;

    float* ws = (float*)d_ws;
    float* Yv     = ws;                                  // [B][D][C]
    float* Yl     = Yv + (long long)BB * DD * CC;        // [B][D][C]
    float* latent = Yl + (long long)BB * DD * CC;        // [B][D][HW]
    float* lat2   = latent + (long long)BB * DD * HWW;   // [B][D][HW]
    float* gram   = lat2 + (long long)BB * DD * HWW;     // [B][D][D]
    float* rs     = gram + (long long)BB * DD * DD;      // [B][D]

    const long long sV = (long long)CC * HWW;   // per-batch feature stride
    const long long sY = (long long)DD * CC;
    const long long sL = (long long)DD * HWW;
    const long long sG = (long long)DD * DD;

    // 1) T = transpose(v2l) into d_out  (xv flat / xv_r view)
    transpose_k<<<dim3(HWW / 32, CC / 32, BB), dim3(32, 8), 0, stream>>>(v2l, out);

    // 2) psi GEMMs (NT): Y = relu(scale*(W @ X^T) + bias)
    gemm_k<128, 128, 16, 8, 8, 0, 1><<<dim3(CC / 128, DD / 128, BB), 256, 0, stream>>>(
        w_v2l, 0, HWW, v2l, sV, HWW, Yv, sY, CC, DD, CC, HWW, g_v2l, b_v2l);
    gemm_k<128, 128, 16, 8, 8, 0, 1><<<dim3(CC / 128, DD / 128, BB), 256, 0, stream>>>(
        w_l2v, 0, HWW, l2v, sV, HWW, Yl, sY, CC, DD, CC, HWW, g_l2v, b_l2v);

    // 3) normalizations
    rownorm_k<<<dim3(DD, BB), 256, 0, stream>>>(Yv);          // over C
    colnorm_k<<<dim3(CC / 256, BB), 256, 0, stream>>>(Yl);    // over D

    // 4) latent = adjV @ T   (NN)  [D,C] x [C,HW]
    gemm_k<128, 128, 16, 8, 8, 1, 0><<<dim3(HWW / 128, DD / 128, BB), 256, 0, stream>>>(
        Yv, sY, CC, out, sV, HWW, latent, sL, HWW, DD, HWW, CC, nullptr, nullptr);

    // 5) gram = latent @ latent^T  (NT)  [D,HW] x [D,HW]^T
    gemm_k<64, 64, 16, 4, 4, 0, 0><<<dim3(DD / 64, DD / 64, BB), 256, 0, stream>>>(
        latent, sL, HWW, latent, sL, HWW, gram, sG, DD, DD, DD, HWW, nullptr, nullptr);

    // 6) rs from gram diag; softmax rows in place -> aff
    latnorm_k<<<dim3(BB * DD / 256), 256, 0, stream>>>(gram, rs);
    softmax_k<<<dim3(DD, BB), 256, 0, stream>>>(gram, rs);

    // 7) lat2 = aff @ latent  (NN)  [D,D] x [D,HW]
    gemm_k<128, 128, 16, 8, 8, 1, 0><<<dim3(HWW / 128, DD / 128, BB), 256, 0, stream>>>(
        gram, sG, DD, latent, sL, HWW, lat2, sL, HWW, DD, HWW, DD, nullptr, nullptr);

    // 8) visible = adjL^T @ lat2  (TN)  [C,D] x [D,HW] -> overwrite d_out
    gemm_k<128, 128, 16, 8, 8, 2, 0><<<dim3(HWW / 128, CC / 128, BB), 256, 0, stream>>>(
        Yl, sY, CC, lat2, sL, HWW, out, sV, HWW, CC, HWW, DD, nullptr, nullptr);
}

// Round 2
// 579.027 us; speedup vs baseline: 1.8655x; 1.8655x over previous
//
#include <hip/hip_runtime.h>
#include <hip/hip_bf16.h>

#define BB 16
#define CC 2048
#define HWW 1024
#define DD 256
#define BN_RSQRT 0.9999950000374997f

typedef short bf16x8 __attribute__((ext_vector_type(8)));
typedef float f32x4 __attribute__((ext_vector_type(4)));
typedef unsigned short u16x8 __attribute__((ext_vector_type(8)));
typedef unsigned short u16;

typedef __attribute__((address_space(1))) const unsigned GU;
typedef __attribute__((address_space(3))) unsigned LU;
__device__ __forceinline__ void gload16(const void* g, void* l) {
    __builtin_amdgcn_global_load_lds((GU*)g, (LU*)l, 16, 0, 0);
}

// ---- bf16 split helpers (RNE) ----
__device__ __forceinline__ unsigned short f2bf(float x) {
    unsigned u = __builtin_bit_cast(unsigned, x);
    unsigned r = u + 0x7FFFu + ((u >> 16) & 1u);
    return (unsigned short)(r >> 16);
}
__device__ __forceinline__ float bf2f(unsigned short h) {
    unsigned u = ((unsigned)h) << 16;
    return __builtin_bit_cast(float, u);
}
__device__ __forceinline__ void split2(float x, unsigned short& hi, unsigned short& lo) {
    hi = f2bf(x);
    lo = f2bf(x - bf2f(hi));
}

// ---------------------------------------------------------------------------
// Elementwise fp32 -> (hi, lo) bf16 planes. n8 = elems/8.
// ---------------------------------------------------------------------------
__global__ __launch_bounds__(256) void split_k(const float* __restrict__ in,
                                               u16* __restrict__ hi, u16* __restrict__ lo,
                                               long long n8) {
    long long i = (long long)blockIdx.x * 256 + threadIdx.x;
    if (i >= n8) return;
    const float4* p = (const float4*)in + i * 2;
    float4 a = p[0], b = p[1];
    float xs[8] = {a.x, a.y, a.z, a.w, b.x, b.y, b.z, b.w};
    u16x8 h, l;
    #pragma unroll
    for (int j = 0; j < 8; ++j) { unsigned short hh, ll; split2(xs[j], hh, ll); h[j] = hh; l[j] = ll; }
    *(u16x8*)(hi + i * 8) = h;
    *(u16x8*)(lo + i * 8) = l;
}

// ---------------------------------------------------------------------------
// B3[b][h][2q+r] = v2l[b][r*1024+h][q]  (split bf16). Block = one (b,h).
// ---------------------------------------------------------------------------
__global__ __launch_bounds__(256) void ileave_k(const float* __restrict__ x,
                                                u16* __restrict__ hi, u16* __restrict__ lo) {
    int h = blockIdx.x, b = blockIdx.y, t = threadIdx.x;
    const float* r0 = x + ((long long)b * CC + h) * HWW + t * 4;
    const float* r1 = r0 + (long long)HWW * HWW;   // row h+1024
    float4 a = *(const float4*)r0;
    float4 c = *(const float4*)r1;
    float xs[8] = {a.x, c.x, a.y, c.y, a.z, c.z, a.w, c.w};
    u16x8 hv, lv;
    #pragma unroll
    for (int j = 0; j < 8; ++j) { unsigned short hh, ll; split2(xs[j], hh, ll); hv[j] = hh; lv[j] = ll; }
    long long o = ((long long)b * HWW + h) * CC + t * 8;
    *(u16x8*)(hi + o) = hv;
    *(u16x8*)(lo + o) = lv;
}

// ---------------------------------------------------------------------------
// Row L2-norm over C of Y[B][D][C] fp32, then IN-PLACE rewrite as split bf16
// planes: row d -> [hi(2048 u16) | lo(2048 u16)] (so plane lda = 4096).
// ---------------------------------------------------------------------------
__global__ __launch_bounds__(256) void rownorm_split_k(float* __restrict__ Y) {
    int d = blockIdx.x, b = blockIdx.y, t = threadIdx.x;
    float* row = Y + ((long long)b * DD + d) * CC;
    float4 v0 = ((const float4*)row)[2 * t];
    float4 v1 = ((const float4*)row)[2 * t + 1];
    float s = v0.x * v0.x + v0.y * v0.y + v0.z * v0.z + v0.w * v0.w
            + v1.x * v1.x + v1.y * v1.y + v1.z * v1.z + v1.w * v1.w;
    for (int off = 32; off > 0; off >>= 1) s += __shfl_down(s, off, 64);
    __shared__ float wsum[4];
    __shared__ float ivs;
    int lane = t & 63, w = t >> 6;
    if (lane == 0) wsum[w] = s;
    __syncthreads();
    if (t == 0) ivs = 1.0f / fmaxf(sqrtf(wsum[0] + wsum[1] + wsum[2] + wsum[3]), 1e-12f);
    __syncthreads();
    float iv = ivs;
    float xs[8] = {v0.x * iv, v0.y * iv, v0.z * iv, v0.w * iv,
                   v1.x * iv, v1.y * iv, v1.z * iv, v1.w * iv};
    u16x8 h, l;
    #pragma unroll
    for (int j = 0; j < 8; ++j) { unsigned short hh, ll; split2(xs[j], hh, ll); h[j] = hh; l[j] = ll; }
    u16* hi = (u16*)row;          // overwrite: all reads of this row already done
    *(u16x8*)(hi + t * 8) = h;
    *(u16x8*)(hi + CC + t * 8) = l;
}

// ---------------------------------------------------------------------------
// Column inv-norm over D of Yl[B][D][C] -> rsc[B][C] (no scaling)
// ---------------------------------------------------------------------------
__global__ __launch_bounds__(256) void colnorm_k(const float* __restrict__ Yl,
                                                 float* __restrict__ rsc) {
    int b = blockIdx.y;
    int c = blockIdx.x * 256 + threadIdx.x;
    const float* base = Yl + (long long)b * DD * CC + c;
    float s = 0.0f;
    for (int d = 0; d < DD; ++d) { float v = base[(long long)d * CC]; s += v * v; }
    rsc[(long long)b * CC + c] = 1.0f / fmaxf(sqrtf(s), 1e-12f);
}

// ---------------------------------------------------------------------------
// Transpose + optional per-input-column scale + split:
// in[B][R][S] fp32 -> hi/lo[B][S][R] bf16 planes.
// ---------------------------------------------------------------------------
template <int HAS_SCALE>
__global__ __launch_bounds__(256) void trans_split_k(const float* __restrict__ in, int R, int S,
                                                     const float* __restrict__ scale,
                                                     u16* __restrict__ hi, u16* __restrict__ lo) {
    __shared__ float tile[32][33];
    int s0 = blockIdx.x * 32, r0 = blockIdx.y * 32, b = blockIdx.z;
    const float* inb = in + (long long)b * R * S;
    int tx = threadIdx.x & 31, ty = threadIdx.x >> 5;  // 32 x 8
    for (int i = ty; i < 32; i += 8)
        tile[i][tx] = inb[(long long)(r0 + i) * S + s0 + tx];
    __syncthreads();
    for (int i = ty; i < 32; i += 8) {
        float v = tile[tx][i];
        if (HAS_SCALE) v *= scale[(long long)b * S + s0 + i];
        unsigned short hh, ll; split2(v, hh, ll);
        long long o = (long long)b * R * S + (long long)(s0 + i) * R + r0 + tx;
        hi[o] = hh; lo[o] = ll;
    }
}

// ---------------------------------------------------------------------------
// Split-bf16 MFMA GEMM, NT form: C[M,N] = sum_k A[m][k] * B[n][k]
// A,B given as hi/lo bf16 planes (row-major, K contiguous).
// 128x128 tile, BK=32, 4 waves (2x2), 64x64 per wave, 16x16x32 MFMA.
// XOR source-swizzle f(r)=(r>>1)&3 on 16B slots (linear LDS for gload_lds).
// EPI: 0 = plain fp32 store, 1 = relu(g[m]*BN_RSQRT * x + b[m])
// ---------------------------------------------------------------------------
template <int EPI>
__global__ __launch_bounds__(256) void mfma_nt(
    const u16* __restrict__ Ahi, const u16* __restrict__ Alo, long long aB, int lda,
    const u16* __restrict__ Bhi, const u16* __restrict__ Blo, long long bB, int ldb,
    float* __restrict__ C, long long cB, int ldc,
    int K, const float* __restrict__ gp, const float* __restrict__ bp)
{
    __shared__ char smem[32768];
    char* sAhi = smem;
    char* sAlo = smem + 8192;
    char* sBhi = smem + 16384;
    char* sBlo = smem + 24576;

    const int t  = threadIdx.x;
    const int bz = blockIdx.z;
    const int n0 = blockIdx.x * 128;
    const int m0 = blockIdx.y * 128;
    const u16* pAhi = Ahi + (long long)bz * aB;
    const u16* pAlo = Alo + (long long)bz * aB;
    const u16* pBhi = Bhi + (long long)bz * bB;
    const u16* pBlo = Blo + (long long)bz * bB;

    // staging coords: thread t -> row r = chunk*64 + (t>>2), 16B slot s = t&3,
    // swizzled source slot s ^ f(r), f(r) = (r>>1)&3 = (t>>3)&3
    const int sr  = t >> 2;
    const int ssw = (t & 3) ^ ((t >> 3) & 3);

    // fragment coords
    const int l  = t & 63, w = t >> 6;
    const int wr = w >> 1, wc = w & 1;
    const int rl = l & 15, kq = l >> 4;
    const int sw = kq ^ ((rl >> 1) & 3);
    const int aOff = (wr * 64 + rl) * 64 + sw * 16;  // byte offset in A planes
    const int bOff = (wc * 64 + rl) * 64 + sw * 16;

    f32x4 acc[4][4];
    #pragma unroll
    for (int i = 0; i < 4; ++i)
        #pragma unroll
        for (int j = 0; j < 4; ++j)
            acc[i][j] = (f32x4){0.f, 0.f, 0.f, 0.f};

    for (int k0 = 0; k0 < K; k0 += 32) {
        long long ga = (long long)(m0 + sr) * lda + k0 + ssw * 8;
        long long gb = (long long)(n0 + sr) * ldb + k0 + ssw * 8;
        gload16(pAhi + ga,                       sAhi + t * 16);
        gload16(pAhi + ga + (long long)64 * lda, sAhi + 4096 + t * 16);
        gload16(pAlo + ga,                       sAlo + t * 16);
        gload16(pAlo + ga + (long long)64 * lda, sAlo + 4096 + t * 16);
        gload16(pBhi + gb,                       sBhi + t * 16);
        gload16(pBhi + gb + (long long)64 * ldb, sBhi + 4096 + t * 16);
        gload16(pBlo + gb,                       sBlo + t * 16);
        gload16(pBlo + gb + (long long)64 * ldb, sBlo + 4096 + t * 16);
        __syncthreads();

        bf16x8 ah[4], al[4], bh[4], bl[4];
        #pragma unroll
        for (int i = 0; i < 4; ++i) {
            ah[i] = *(const bf16x8*)(sAhi + aOff + i * 1024);
            al[i] = *(const bf16x8*)(sAlo + aOff + i * 1024);
            bh[i] = *(const bf16x8*)(sBhi + bOff + i * 1024);
            bl[i] = *(const bf16x8*)(sBlo + bOff + i * 1024);
        }
        #pragma unroll
        for (int i = 0; i < 4; ++i)
            #pragma unroll
            for (int j = 0; j < 4; ++j) {
                acc[i][j] = __builtin_amdgcn_mfma_f32_16x16x32_bf16(al[i], bh[j], acc[i][j], 0, 0, 0);
                acc[i][j] = __builtin_amdgcn_mfma_f32_16x16x32_bf16(ah[i], bl[j], acc[i][j], 0, 0, 0);
                acc[i][j] = __builtin_amdgcn_mfma_f32_16x16x32_bf16(ah[i], bh[j], acc[i][j], 0, 0, 0);
            }
        __syncthreads();
    }

    float* Cb = C + (long long)bz * cB;
    #pragma unroll
    for (int i = 0; i < 4; ++i) {
        #pragma unroll
        for (int r = 0; r < 4; ++r) {
            int row = m0 + wr * 64 + i * 16 + kq * 4 + r;
            float sc = 1.0f, bi = 0.0f;
            if (EPI) { sc = gp[row] * BN_RSQRT; bi = bp[row]; }
            #pragma unroll
            for (int j = 0; j < 4; ++j) {
                int col = n0 + wc * 64 + j * 16 + rl;
                float v = acc[i][j][r];
                if (EPI) v = fmaxf(fmaf(v, sc, bi), 0.0f);
                Cb[(long long)row * ldc + col] = v;
            }
        }
    }
}

// ---------------------------------------------------------------------------
// fp32 tiled GEMM (kept for gram + aff@latent).
// LAYOUT: 0 = NT, 1 = NN.  EPI unused here (0).
// ---------------------------------------------------------------------------
template <int BM, int BN, int BK, int TM, int TN, int LAYOUT, int EPI>
__global__ __launch_bounds__(256) void gemm_k(
    const float* __restrict__ A, long long aBatch, int lda,
    const float* __restrict__ Bp, long long bBatch, int ldb,
    float* __restrict__ Cp, long long cBatch, int ldc,
    int M, int N, int K,
    const float* __restrict__ gp, const float* __restrict__ biasp)
{
    constexpr int THREADS = (BM / TM) * (BN / TN);
    __shared__ float As[BK][BM + 4];
    __shared__ float Bs[BK][BN + 4];

    int b = blockIdx.z;
    const float* Ab = A  + (long long)b * aBatch;
    const float* Bb = Bp + (long long)b * bBatch;
    float*       Cb = Cp + (long long)b * cBatch;

    int n0 = blockIdx.x * BN;
    int m0 = blockIdx.y * BM;
    int t  = threadIdx.x;
    int tx = t % (BN / TN);
    int ty = t / (BN / TN);

    float acc[TM][TN] = {};

    for (int k0 = 0; k0 < K; k0 += BK) {
        {
            constexpr int V = (BM * BK / 4) / THREADS;
            #pragma unroll
            for (int i = 0; i < V; ++i) {
                int idx = t + i * THREADS;
                int r = idx / (BK / 4), c4 = idx % (BK / 4);
                float4 v = *(const float4*)&Ab[(long long)(m0 + r) * lda + k0 + c4 * 4];
                As[c4 * 4 + 0][r] = v.x;
                As[c4 * 4 + 1][r] = v.y;
                As[c4 * 4 + 2][r] = v.z;
                As[c4 * 4 + 3][r] = v.w;
            }
        }
        if (LAYOUT == 0) {
            constexpr int V = (BN * BK / 4) / THREADS;
            #pragma unroll
            for (int i = 0; i < V; ++i) {
                int idx = t + i * THREADS;
                int r = idx / (BK / 4), c4 = idx % (BK / 4);
                float4 v = *(const float4*)&Bb[(long long)(n0 + r) * ldb + k0 + c4 * 4];
                Bs[c4 * 4 + 0][r] = v.x;
                Bs[c4 * 4 + 1][r] = v.y;
                Bs[c4 * 4 + 2][r] = v.z;
                Bs[c4 * 4 + 3][r] = v.w;
            }
        } else {
            constexpr int V = (BK * BN / 4) / THREADS;
            #pragma unroll
            for (int i = 0; i < V; ++i) {
                int idx = t + i * THREADS;
                int r = idx / (BN / 4), c4 = idx % (BN / 4);
                float4 v = *(const float4*)&Bb[(long long)(k0 + r) * ldb + n0 + c4 * 4];
                *(float4*)&Bs[r][c4 * 4] = v;
            }
        }
        __syncthreads();

        #pragma unroll
        for (int k = 0; k < BK; ++k) {
            float aR[TM], bR[TN];
            #pragma unroll
            for (int i = 0; i < TM; ++i) aR[i] = As[k][ty * TM + i];
            #pragma unroll
            for (int j = 0; j < TN; ++j) bR[j] = Bs[k][tx * TN + j];
            #pragma unroll
            for (int i = 0; i < TM; ++i)
                #pragma unroll
                for (int j = 0; j < TN; ++j)
                    acc[i][j] = fmaf(aR[i], bR[j], acc[i][j]);
        }
        __syncthreads();
    }

    #pragma unroll
    for (int i = 0; i < TM; ++i) {
        int m = m0 + ty * TM + i;
        #pragma unroll
        for (int j0 = 0; j0 < TN; j0 += 4) {
            float4 v;
            v.x = acc[i][j0 + 0]; v.y = acc[i][j0 + 1];
            v.z = acc[i][j0 + 2]; v.w = acc[i][j0 + 3];
            *(float4*)&Cb[(long long)m * ldc + n0 + tx * TN + j0] = v;
        }
    }
}

// ---------------------------------------------------------------------------
__global__ __launch_bounds__(256) void latnorm_k(const float* __restrict__ G,
                                                 float* __restrict__ rs) {
    int i = blockIdx.x * 256 + threadIdx.x;
    int b = i >> 8, d = i & 255;
    float v = G[((long long)b * DD + d) * DD + d];
    rs[i] = 1.0f / fmaxf(sqrtf(v), 1e-12f);
}

__global__ __launch_bounds__(256) void softmax_k(float* __restrict__ G,
                                                 const float* __restrict__ rs) {
    int d = blockIdx.x, b = blockIdx.y;
    float* row = G + ((long long)b * DD + d) * DD;
    const float* rsb = rs + (long long)b * DD;
    int t = threadIdx.x;
    float lg = row[t] * rsb[d] * rsb[t];

    float m = lg;
    for (int off = 32; off > 0; off >>= 1) m = fmaxf(m, __shfl_down(m, off, 64));
    __shared__ float wsm[4];
    __shared__ float bm, bs;
    int lane = t & 63, w = t >> 6;
    if (lane == 0) wsm[w] = m;
    __syncthreads();
    if (t == 0) bm = fmaxf(fmaxf(wsm[0], wsm[1]), fmaxf(wsm[2], wsm[3]));
    __syncthreads();
    float e = expf(lg - bm);
    float s = e;
    for (int off = 32; off > 0; off >>= 1) s += __shfl_down(s, off, 64);
    if (lane == 0) wsm[w] = s;
    __syncthreads();
    if (t == 0) bs = wsm[0] + wsm[1] + wsm[2] + wsm[3];
    __syncthreads();
    row[t] = e / bs;
}

// ---------------------------------------------------------------------------
extern "C" void kernel_launch(void* const* d_in, const int* in_sizes, int n_in,
                              void* d_out, int out_size, void* d_ws, size_t ws_size,
                              hipStream_t stream) {
    const float* v2l   = (const float*)d_in[0];
    const float* l2v   = (const float*)d_in[1];
    const float* w_v2l = (const float*)d_in[2];
    const float* g_v2l = (const float*)d_in[3];
    const float* b_v2l = (const float*)d_in[4];
    const float* w_l2v = (const float*)d_in[5];
    const float* g_l2v = (const float*)d_in[6];
    const float* b_l2v = (const float*)d_in[7];
    float* out = (float*)d_out;

    // d_out doubles as the big bf16 plane region (Xv -> Xl -> B3), 134,217,728 B
    u16* bigHi = (u16*)d_out;
    u16* bigLo = bigHi + (long long)33554432;

    char* W = (char*)d_ws;
    float* Yv     = (float*)(W + 0);            // 33,554,432 B (fp32 -> in-place planes)
    float* Yl     = (float*)(W + 33554432);     // 33,554,432 B
    u16*   YltHi  = (u16*)(W + 67108864);       // 16,777,216 B
    u16*   YltLo  = (u16*)(W + 83886080);       // 16,777,216 B
    float* latent = (float*)(W + 100663296);    // 16,777,216 B
    float* lat2   = (float*)(W + 117440512);    // 16,777,216 B
    u16*   l2tHi  = (u16*)(W + 134217728);      //  8,388,608 B
    u16*   l2tLo  = (u16*)(W + 142606336);      //  8,388,608 B
    float* gram   = (float*)(W + 150994944);    //  4,194,304 B
    float* rs     = (float*)(W + 155189248);    //     16,384 B
    float* rsc    = (float*)(W + 155205632);    //    131,072 B
    u16*   WvHi   = (u16*)(W + 155336704);      //    524,288 B each
    u16*   WvLo   = WvHi + 262144;
    u16*   WlHi   = WvLo + 262144;
    u16*   WlLo   = WlHi + 262144;

    const long long sY = (long long)DD * CC;        // 524,288
    const long long sL = (long long)DD * HWW;       // 262,144
    const long long sG = (long long)DD * DD;        // 65,536
    const long long sX = (long long)CC * HWW;       // 2,097,152
    const long long sB3 = (long long)HWW * CC;      // 2,097,152
    const long long sYn = (long long)DD * 4096;     // 1,048,576 (in-place plane stride)
    const long long sYt = (long long)CC * DD;       // 524,288
    const long long sL2t = (long long)HWW * DD;     // 262,144

    // weights -> split planes
    split_k<<<128, 256, 0, stream>>>(w_v2l, WvHi, WvLo, 32768);
    split_k<<<128, 256, 0, stream>>>(w_l2v, WlHi, WlLo, 32768);

    // Xv = split(v2l) [C,HW]; G1: Yv = relu(sc*(W_v2l . Xv^T) + b)
    split_k<<<16384, 256, 0, stream>>>(v2l, bigHi, bigLo, 4194304);
    mfma_nt<1><<<dim3(16, 2, BB), 256, 0, stream>>>(
        WvHi, WvLo, 0, HWW, bigHi, bigLo, sX, HWW, Yv, sY, CC, HWW, g_v2l, b_v2l);

    // row-normalize Yv over C, rewrite in place as split planes (lda=4096)
    rownorm_split_k<<<dim3(DD, BB), 256, 0, stream>>>(Yv);

    // Xl = split(l2v); G2: Yl
    split_k<<<16384, 256, 0, stream>>>(l2v, bigHi, bigLo, 4194304);
    mfma_nt<1><<<dim3(16, 2, BB), 256, 0, stream>>>(
        WlHi, WlLo, 0, HWW, bigHi, bigLo, sX, HWW, Yl, sY, CC, HWW, g_l2v, b_l2v);

    // column inv-norms of Yl over D; Ylt = split(transpose(Yl) * rsc) [C,D]
    colnorm_k<<<dim3(CC / 256, BB), 256, 0, stream>>>(Yl, rsc);
    trans_split_k<1><<<dim3(CC / 32, DD / 32, BB), 256, 0, stream>>>(
        Yl, DD, CC, rsc, YltHi, YltLo);

    // B3 = interleaved reinterpret of v2l; G3: latent = Yvn . B3^T  [D,HW]
    ileave_k<<<dim3(HWW, BB), 256, 0, stream>>>(v2l, bigHi, bigLo);
    mfma_nt<0><<<dim3(8, 2, BB), 256, 0, stream>>>(
        (const u16*)Yv, (const u16*)Yv + CC, sYn, 4096,
        bigHi, bigLo, sB3, CC, latent, sL, HWW, CC, nullptr, nullptr);

    // gram = latent . latent^T (fp32 NT)
    gemm_k<64, 64, 16, 4, 4, 0, 0><<<dim3(4, 4, BB), 256, 0, stream>>>(
        latent, sL, HWW, latent, sL, HWW, gram, sG, DD, DD, DD, HWW, nullptr, nullptr);

    // softmax(normalized gram)
    latnorm_k<<<dim3(BB * DD / 256), 256, 0, stream>>>(gram, rs);
    softmax_k<<<dim3(DD, BB), 256, 0, stream>>>(gram, rs);

    // lat2 = aff . latent (fp32 NN)
    gemm_k<128, 128, 16, 8, 8, 1, 0><<<dim3(8, 2, BB), 256, 0, stream>>>(
        gram, sG, DD, latent, sL, HWW, lat2, sL, HWW, DD, HWW, DD, nullptr, nullptr);

    // lat2t = split(transpose(lat2)) [HW,D]
    trans_split_k<0><<<dim3(HWW / 32, DD / 32, BB), 256, 0, stream>>>(
        lat2, DD, HWW, nullptr, l2tHi, l2tLo);

    // G6: out = Ylt . lat2t^T  [C,HW]
    mfma_nt<0><<<dim3(8, 16, BB), 256, 0, stream>>>(
        YltHi, YltLo, sYt, DD, l2tHi, l2tLo, sL2t, DD, out, sX, HWW, DD, nullptr, nullptr);
}

// Round 3
// 462.213 us; speedup vs baseline: 2.3370x; 1.2527x over previous
//
#include <hip/hip_runtime.h>
#include <hip/hip_bf16.h>

#define BB 16
#define CC 2048
#define HWW 1024
#define DD 256
#define BN_RSQRT 0.9999950000374997f

typedef short bf16x8 __attribute__((ext_vector_type(8)));
typedef float f32x4 __attribute__((ext_vector_type(4)));
typedef unsigned short u16x8 __attribute__((ext_vector_type(8)));
typedef unsigned short u16;

// ---- bf16 split helpers (RNE) ----
__device__ __forceinline__ unsigned short f2bf(float x) {
    unsigned u = __builtin_bit_cast(unsigned, x);
    unsigned r = u + 0x7FFFu + ((u >> 16) & 1u);
    return (unsigned short)(r >> 16);
}
__device__ __forceinline__ float bf2f(unsigned short h) {
    unsigned u = ((unsigned)h) << 16;
    return __builtin_bit_cast(float, u);
}
__device__ __forceinline__ void split2(float x, unsigned short& hi, unsigned short& lo) {
    hi = f2bf(x);
    lo = f2bf(x - bf2f(hi));
}
__device__ __forceinline__ void split16(const float* v, u16x8& h0, u16x8& h1,
                                        u16x8& l0, u16x8& l1) {
    #pragma unroll
    for (int j = 0; j < 8; ++j) { unsigned short hh, ll; split2(v[j], hh, ll); h0[j] = hh; l0[j] = ll; }
    #pragma unroll
    for (int j = 0; j < 8; ++j) { unsigned short hh, ll; split2(v[8 + j], hh, ll); h1[j] = hh; l1[j] = ll; }
}

// ---------------------------------------------------------------------------
// Unified split-bf16 MFMA GEMM, NT form: C[M,N] = sum_k A[m][k]*B[n][k]
// BM=128 fixed, BK=32, 4 waves, double-buffered LDS, reg-staged (split on the
// fly), ONE barrier per K-step, XOR slot-swizzle (write & read sides).
// AFMT: 0 = fp32 row-major [m][k] (Ap)       1 = bf16 hi/lo planes (Ap,Ap2)
// BFMT: 0 = fp32 row-major [n][k] (Bp)       1 = planes (Bp,Bp2)
//       2 = fp32 ileave: B[h][2q+r] = Bp[(r*1024+h)][q]  (ldb fixed = HWW)
// EPI : 0 = plain fp32 store   1 = relu(g[m]*BN_RSQRT*x + b[m])
// ---------------------------------------------------------------------------
template <int BN_, int AFMT, int BFMT, int EPI>
__global__ __launch_bounds__(256) void mfma_gemm(
    const void* __restrict__ Ap, const void* __restrict__ Ap2, long long aB, int lda,
    const void* __restrict__ Bp, const void* __restrict__ Bp2, long long bB, int ldb,
    float* __restrict__ Cp, long long cB, int ldc,
    int K, const float* __restrict__ gp, const float* __restrict__ bpb)
{
    constexpr int NJ   = BN_ / 32;          // B frags per wave
    constexpr int BNB  = BN_ * 64;          // bytes per B plane
    constexpr int BUFB = 16384 + BN_ * 128; // bytes per LDS buffer
    __shared__ __attribute__((aligned(16))) char smem[2][BUFB];

    // ---- bijective XCD-chunk block swizzle (nwg divisible by 8) ----
    const int gx = gridDim.x, gy = gridDim.y;
    int nwg = gx * gy * gridDim.z;
    int id = blockIdx.x + gx * (blockIdx.y + gy * blockIdx.z);
    int chunk = nwg >> 3;
    int nid = (id & 7) * chunk + (id >> 3);
    int bx = nid % gx;
    int tmp = nid / gx;
    int by = tmp % gy;
    int bz = tmp / gy;

    const int t  = threadIdx.x;
    const int n0 = bx * BN_;
    const int m0 = by * 128;

    // ---- staging task coords ----
    const int ar = t >> 1, ag = t & 1;             // A: row, k-half
    const int af = (ar >> 1) & 3;
    const int as0 = (2 * ag) ^ af, as1 = (2 * ag + 1) ^ af;
    const bool bact = (BN_ == 128) || (t < 2 * BN_);
    const int br = (t >> 1) & (BN_ - 1), bg = t & 1;
    const int bf = (br >> 1) & 3;
    const int bs0 = (2 * bg) ^ bf, bs1 = (2 * bg + 1) ^ bf;

    // ---- fragment coords ----
    const int l  = t & 63, w = t >> 6;
    const int wr = w >> 1, wc = w & 1;
    const int rl = l & 15, kq = l >> 4;
    const int sw = kq ^ ((rl >> 1) & 3);
    const int aoff = (wr * 64 + rl) * 64 + sw * 16;
    const int boff = (wc * (BN_ / 2) + rl) * 64 + sw * 16;

    // ---- per-format base pointers ----
    const float* Afp = (const float*)Ap + (long long)bz * aB;
    const u16*   Ahp = (const u16*)Ap  + (long long)bz * aB;
    const u16*   Alp = (const u16*)Ap2 + (long long)bz * aB;
    const float* Bfp = (const float*)Bp + (long long)bz * bB;
    const u16*   Bhp = (const u16*)Bp  + (long long)bz * bB;
    const u16*   Blp = (const u16*)Bp2 + (long long)bz * bB;

    // staged regs
    float4 ra0, ra1, ra2, ra3, rb0, rb1, rb2, rb3;
    u16x8 rah0, rah1, ral0, ral1, rbh0, rbh1, rbl0, rbl1;

    auto loadA = [&](int k0) {
        if constexpr (AFMT == 0) {
            const float* p = Afp + (long long)(m0 + ar) * lda + k0 + ag * 16;
            ra0 = *(const float4*)(p);
            ra1 = *(const float4*)(p + 4);
            ra2 = *(const float4*)(p + 8);
            ra3 = *(const float4*)(p + 12);
        } else {
            const u16* ph = Ahp + (long long)(m0 + ar) * lda + k0 + ag * 16;
            const u16* pl = Alp + (long long)(m0 + ar) * lda + k0 + ag * 16;
            rah0 = *(const u16x8*)(ph);
            rah1 = *(const u16x8*)(ph + 8);
            ral0 = *(const u16x8*)(pl);
            ral1 = *(const u16x8*)(pl + 8);
        }
    };
    auto loadB = [&](int k0) {
        if (!bact) return;
        if constexpr (BFMT == 0) {
            const float* p = Bfp + (long long)(n0 + br) * ldb + k0 + bg * 16;
            rb0 = *(const float4*)(p);
            rb1 = *(const float4*)(p + 4);
            rb2 = *(const float4*)(p + 8);
            rb3 = *(const float4*)(p + 12);
        } else if constexpr (BFMT == 1) {
            const u16* ph = Bhp + (long long)(n0 + br) * ldb + k0 + bg * 16;
            const u16* pl = Blp + (long long)(n0 + br) * ldb + k0 + bg * 16;
            rbh0 = *(const u16x8*)(ph);
            rbh1 = *(const u16x8*)(ph + 8);
            rbl0 = *(const u16x8*)(pl);
            rbl1 = *(const u16x8*)(pl + 8);
        } else {
            int q0 = (k0 >> 1) + bg * 8;
            const float* p0 = Bfp + (long long)(n0 + br) * HWW + q0;
            const float* p1 = p0 + (long long)HWW * HWW;
            rb0 = *(const float4*)(p0);
            rb1 = *(const float4*)(p0 + 4);
            rb2 = *(const float4*)(p1);
            rb3 = *(const float4*)(p1 + 4);
        }
    };
    auto stageWrite = [&](char* sb) {
        if constexpr (AFMT == 0) {
            float v[16] = {ra0.x, ra0.y, ra0.z, ra0.w, ra1.x, ra1.y, ra1.z, ra1.w,
                           ra2.x, ra2.y, ra2.z, ra2.w, ra3.x, ra3.y, ra3.z, ra3.w};
            u16x8 h0, h1, l0, l1;
            split16(v, h0, h1, l0, l1);
            *(u16x8*)(sb + ar * 64 + as0 * 16) = h0;
            *(u16x8*)(sb + ar * 64 + as1 * 16) = h1;
            *(u16x8*)(sb + 8192 + ar * 64 + as0 * 16) = l0;
            *(u16x8*)(sb + 8192 + ar * 64 + as1 * 16) = l1;
        } else {
            *(u16x8*)(sb + ar * 64 + as0 * 16) = rah0;
            *(u16x8*)(sb + ar * 64 + as1 * 16) = rah1;
            *(u16x8*)(sb + 8192 + ar * 64 + as0 * 16) = ral0;
            *(u16x8*)(sb + 8192 + ar * 64 + as1 * 16) = ral1;
        }
        if (bact) {
            char* sB = sb + 16384;
            if constexpr (BFMT == 1) {
                *(u16x8*)(sB + br * 64 + bs0 * 16) = rbh0;
                *(u16x8*)(sB + br * 64 + bs1 * 16) = rbh1;
                *(u16x8*)(sB + BNB + br * 64 + bs0 * 16) = rbl0;
                *(u16x8*)(sB + BNB + br * 64 + bs1 * 16) = rbl1;
            } else {
                float v[16];
                if constexpr (BFMT == 0) {
                    float vv[16] = {rb0.x, rb0.y, rb0.z, rb0.w, rb1.x, rb1.y, rb1.z, rb1.w,
                                    rb2.x, rb2.y, rb2.z, rb2.w, rb3.x, rb3.y, rb3.z, rb3.w};
                    #pragma unroll
                    for (int j = 0; j < 16; ++j) v[j] = vv[j];
                } else {
                    float vv[16] = {rb0.x, rb2.x, rb0.y, rb2.y, rb0.z, rb2.z, rb0.w, rb2.w,
                                    rb1.x, rb3.x, rb1.y, rb3.y, rb1.z, rb3.z, rb1.w, rb3.w};
                    #pragma unroll
                    for (int j = 0; j < 16; ++j) v[j] = vv[j];
                }
                u16x8 h0, h1, l0, l1;
                split16(v, h0, h1, l0, l1);
                *(u16x8*)(sB + br * 64 + bs0 * 16) = h0;
                *(u16x8*)(sB + br * 64 + bs1 * 16) = h1;
                *(u16x8*)(sB + BNB + br * 64 + bs0 * 16) = l0;
                *(u16x8*)(sB + BNB + br * 64 + bs1 * 16) = l1;
            }
        }
    };

    f32x4 acc[4][NJ];
    #pragma unroll
    for (int i = 0; i < 4; ++i)
        #pragma unroll
        for (int j = 0; j < NJ; ++j)
            acc[i][j] = (f32x4){0.f, 0.f, 0.f, 0.f};

    // prologue
    loadA(0);
    loadB(0);
    stageWrite(smem[0]);
    __syncthreads();

    const int NIT = K >> 5;
    for (int it = 0; it < NIT; ++it) {
        char* sb = smem[it & 1];
        char* sn = smem[(it + 1) & 1];
        const bool more = (it + 1 < NIT);
        if (more) { loadA((it + 1) << 5); loadB((it + 1) << 5); }

        bf16x8 fah[4], fal[4], fbh[NJ], fbl[NJ];
        #pragma unroll
        for (int i = 0; i < 4; ++i) {
            fah[i] = *(const bf16x8*)(sb + aoff + i * 1024);
            fal[i] = *(const bf16x8*)(sb + 8192 + aoff + i * 1024);
        }
        #pragma unroll
        for (int j = 0; j < NJ; ++j) {
            fbh[j] = *(const bf16x8*)(sb + 16384 + boff + j * 1024);
            fbl[j] = *(const bf16x8*)(sb + 16384 + BNB + boff + j * 1024);
        }
        #pragma unroll
        for (int i = 0; i < 4; ++i)
            #pragma unroll
            for (int j = 0; j < NJ; ++j) {
                acc[i][j] = __builtin_amdgcn_mfma_f32_16x16x32_bf16(fal[i], fbh[j], acc[i][j], 0, 0, 0);
                acc[i][j] = __builtin_amdgcn_mfma_f32_16x16x32_bf16(fah[i], fbl[j], acc[i][j], 0, 0, 0);
                acc[i][j] = __builtin_amdgcn_mfma_f32_16x16x32_bf16(fah[i], fbh[j], acc[i][j], 0, 0, 0);
            }
        if (more) stageWrite(sn);
        __syncthreads();
    }

    // epilogue
    float* Cb = Cp + (long long)bz * cB;
    #pragma unroll
    for (int i = 0; i < 4; ++i) {
        #pragma unroll
        for (int r = 0; r < 4; ++r) {
            int row = m0 + wr * 64 + i * 16 + kq * 4 + r;
            float sc = 1.0f, bi = 0.0f;
            if (EPI) { sc = gp[row] * BN_RSQRT; bi = bpb[row]; }
            #pragma unroll
            for (int j = 0; j < NJ; ++j) {
                int col = n0 + wc * (BN_ / 2) + j * 16 + rl;
                float v = acc[i][j][r];
                if (EPI) v = fmaxf(fmaf(v, sc, bi), 0.0f);
                Cb[(long long)row * ldc + col] = v;
            }
        }
    }
}

// ---------------------------------------------------------------------------
// Row L2-norm over C of Y[B][D][C] fp32, then IN-PLACE rewrite as split bf16
// planes: row d -> [hi(2048 u16) | lo(2048 u16)]  (plane lda = 4096)
// ---------------------------------------------------------------------------
__global__ __launch_bounds__(256) void rownorm_split_k(float* __restrict__ Y) {
    int d = blockIdx.x, b = blockIdx.y, t = threadIdx.x;
    float* row = Y + ((long long)b * DD + d) * CC;
    float4 v0 = ((const float4*)row)[2 * t];
    float4 v1 = ((const float4*)row)[2 * t + 1];
    float s = v0.x * v0.x + v0.y * v0.y + v0.z * v0.z + v0.w * v0.w
            + v1.x * v1.x + v1.y * v1.y + v1.z * v1.z + v1.w * v1.w;
    for (int off = 32; off > 0; off >>= 1) s += __shfl_down(s, off, 64);
    __shared__ float wsum[4];
    __shared__ float ivs;
    int lane = t & 63, w = t >> 6;
    if (lane == 0) wsum[w] = s;
    __syncthreads();
    if (t == 0) ivs = 1.0f / fmaxf(sqrtf(wsum[0] + wsum[1] + wsum[2] + wsum[3]), 1e-12f);
    __syncthreads();
    float iv = ivs;
    float xs[8] = {v0.x * iv, v0.y * iv, v0.z * iv, v0.w * iv,
                   v1.x * iv, v1.y * iv, v1.z * iv, v1.w * iv};
    u16x8 h, l2;
    #pragma unroll
    for (int j = 0; j < 8; ++j) { unsigned short hh, ll; split2(xs[j], hh, ll); h[j] = hh; l2[j] = ll; }
    u16* hi = (u16*)row;
    *(u16x8*)(hi + t * 8) = h;
    *(u16x8*)(hi + CC + t * 8) = l2;
}

// ---------------------------------------------------------------------------
__global__ __launch_bounds__(256) void colnorm_k(const float* __restrict__ Yl,
                                                 float* __restrict__ rsc) {
    int b = blockIdx.y;
    int c = blockIdx.x * 256 + threadIdx.x;
    const float* base = Yl + (long long)b * DD * CC + c;
    float s = 0.0f;
    for (int d = 0; d < DD; ++d) { float v = base[(long long)d * CC]; s += v * v; }
    rsc[(long long)b * CC + c] = 1.0f / fmaxf(sqrtf(s), 1e-12f);
}

// ---------------------------------------------------------------------------
template <int HAS_SCALE>
__global__ __launch_bounds__(256) void trans_split_k(const float* __restrict__ in, int R, int S,
                                                     const float* __restrict__ scale,
                                                     u16* __restrict__ hi, u16* __restrict__ lo) {
    __shared__ float tile[32][33];
    int s0 = blockIdx.x * 32, r0 = blockIdx.y * 32, b = blockIdx.z;
    const float* inb = in + (long long)b * R * S;
    int tx = threadIdx.x & 31, ty = threadIdx.x >> 5;
    for (int i = ty; i < 32; i += 8)
        tile[i][tx] = inb[(long long)(r0 + i) * S + s0 + tx];
    __syncthreads();
    for (int i = ty; i < 32; i += 8) {
        float v = tile[tx][i];
        if (HAS_SCALE) v *= scale[(long long)b * S + s0 + i];
        unsigned short hh, ll; split2(v, hh, ll);
        long long o = (long long)b * R * S + (long long)(s0 + i) * R + r0 + tx;
        hi[o] = hh; lo[o] = ll;
    }
}

// ---------------------------------------------------------------------------
// fp32 tiled GEMM (gram NT + aff NN)
// ---------------------------------------------------------------------------
template <int BM, int BN, int BK, int TM, int TN, int LAYOUT>
__global__ __launch_bounds__(256) void gemm_k(
    const float* __restrict__ A, long long aBatch, int lda,
    const float* __restrict__ Bp, long long bBatch, int ldb,
    float* __restrict__ Cp, long long cBatch, int ldc, int K)
{
    constexpr int THREADS = (BM / TM) * (BN / TN);
    __shared__ float As[BK][BM + 4];
    __shared__ float Bs[BK][BN + 4];

    int b = blockIdx.z;
    const float* Ab = A  + (long long)b * aBatch;
    const float* Bb = Bp + (long long)b * bBatch;
    float*       Cb = Cp + (long long)b * cBatch;

    int n0 = blockIdx.x * BN;
    int m0 = blockIdx.y * BM;
    int t  = threadIdx.x;
    int tx = t % (BN / TN);
    int ty = t / (BN / TN);

    float acc[TM][TN] = {};

    for (int k0 = 0; k0 < K; k0 += BK) {
        {
            constexpr int V = (BM * BK / 4) / THREADS;
            #pragma unroll
            for (int i = 0; i < V; ++i) {
                int idx = t + i * THREADS;
                int r = idx / (BK / 4), c4 = idx % (BK / 4);
                float4 v = *(const float4*)&Ab[(long long)(m0 + r) * lda + k0 + c4 * 4];
                As[c4 * 4 + 0][r] = v.x;
                As[c4 * 4 + 1][r] = v.y;
                As[c4 * 4 + 2][r] = v.z;
                As[c4 * 4 + 3][r] = v.w;
            }
        }
        if (LAYOUT == 0) {
            constexpr int V = (BN * BK / 4) / THREADS;
            #pragma unroll
            for (int i = 0; i < V; ++i) {
                int idx = t + i * THREADS;
                int r = idx / (BK / 4), c4 = idx % (BK / 4);
                float4 v = *(const float4*)&Bb[(long long)(n0 + r) * ldb + k0 + c4 * 4];
                Bs[c4 * 4 + 0][r] = v.x;
                Bs[c4 * 4 + 1][r] = v.y;
                Bs[c4 * 4 + 2][r] = v.z;
                Bs[c4 * 4 + 3][r] = v.w;
            }
        } else {
            constexpr int V = (BK * BN / 4) / THREADS;
            #pragma unroll
            for (int i = 0; i < V; ++i) {
                int idx = t + i * THREADS;
                int r = idx / (BN / 4), c4 = idx % (BN / 4);
                float4 v = *(const float4*)&Bb[(long long)(k0 + r) * ldb + n0 + c4 * 4];
                *(float4*)&Bs[r][c4 * 4] = v;
            }
        }
        __syncthreads();

        #pragma unroll
        for (int k = 0; k < BK; ++k) {
            float aR[TM], bR[TN];
            #pragma unroll
            for (int i = 0; i < TM; ++i) aR[i] = As[k][ty * TM + i];
            #pragma unroll
            for (int j = 0; j < TN; ++j) bR[j] = Bs[k][tx * TN + j];
            #pragma unroll
            for (int i = 0; i < TM; ++i)
                #pragma unroll
                for (int j = 0; j < TN; ++j)
                    acc[i][j] = fmaf(aR[i], bR[j], acc[i][j]);
        }
        __syncthreads();
    }

    #pragma unroll
    for (int i = 0; i < TM; ++i) {
        int m = m0 + ty * TM + i;
        #pragma unroll
        for (int j0 = 0; j0 < TN; j0 += 4) {
            float4 v;
            v.x = acc[i][j0 + 0]; v.y = acc[i][j0 + 1];
            v.z = acc[i][j0 + 2]; v.w = acc[i][j0 + 3];
            *(float4*)&Cb[(long long)m * ldc + n0 + tx * TN + j0] = v;
        }
    }
}

// ---------------------------------------------------------------------------
__global__ __launch_bounds__(256) void latnorm_k(const float* __restrict__ G,
                                                 float* __restrict__ rs) {
    int i = blockIdx.x * 256 + threadIdx.x;
    int b = i >> 8, d = i & 255;
    float v = G[((long long)b * DD + d) * DD + d];
    rs[i] = 1.0f / fmaxf(sqrtf(v), 1e-12f);
}

__global__ __launch_bounds__(256) void softmax_k(float* __restrict__ G,
                                                 const float* __restrict__ rs) {
    int d = blockIdx.x, b = blockIdx.y;
    float* row = G + ((long long)b * DD + d) * DD;
    const float* rsb = rs + (long long)b * DD;
    int t = threadIdx.x;
    float lg = row[t] * rsb[d] * rsb[t];

    float m = lg;
    for (int off = 32; off > 0; off >>= 1) m = fmaxf(m, __shfl_down(m, off, 64));
    __shared__ float wsm[4];
    __shared__ float bm, bs;
    int lane = t & 63, w = t >> 6;
    if (lane == 0) wsm[w] = m;
    __syncthreads();
    if (t == 0) bm = fmaxf(fmaxf(wsm[0], wsm[1]), fmaxf(wsm[2], wsm[3]));
    __syncthreads();
    float e = expf(lg - bm);
    float s = e;
    for (int off = 32; off > 0; off >>= 1) s += __shfl_down(s, off, 64);
    if (lane == 0) wsm[w] = s;
    __syncthreads();
    if (t == 0) bs = wsm[0] + wsm[1] + wsm[2] + wsm[3];
    __syncthreads();
    row[t] = e / bs;
}

// ---------------------------------------------------------------------------
extern "C" void kernel_launch(void* const* d_in, const int* in_sizes, int n_in,
                              void* d_out, int out_size, void* d_ws, size_t ws_size,
                              hipStream_t stream) {
    const float* v2l   = (const float*)d_in[0];
    const float* l2v   = (const float*)d_in[1];
    const float* w_v2l = (const float*)d_in[2];
    const float* g_v2l = (const float*)d_in[3];
    const float* b_v2l = (const float*)d_in[4];
    const float* w_l2v = (const float*)d_in[5];
    const float* g_l2v = (const float*)d_in[6];
    const float* b_l2v = (const float*)d_in[7];
    float* out = (float*)d_out;

    char* W = (char*)d_ws;
    float* Yv     = (float*)(W + 0);            // 32MB fp32 -> in-place planes
    float* Yl     = (float*)(W + 33554432);     // 32MB
    u16*   YltHi  = (u16*)(W + 67108864);       // 16MB
    u16*   YltLo  = (u16*)(W + 83886080);       // 16MB
    float* latent = (float*)(W + 100663296);    // 16MB
    float* lat2   = (float*)(W + 117440512);    // 16MB
    u16*   l2tHi  = (u16*)(W + 134217728);      //  8MB
    u16*   l2tLo  = (u16*)(W + 142606336);      //  8MB
    float* gram   = (float*)(W + 150994944);    //  4MB
    float* rs     = (float*)(W + 155189248);
    float* rsc    = (float*)(W + 155205632);

    const long long sY  = (long long)DD * CC;      // 524288
    const long long sL  = (long long)DD * HWW;     // 262144
    const long long sG  = (long long)DD * DD;      // 65536
    const long long sX  = (long long)CC * HWW;     // 2097152
    const long long sYp = (long long)DD * 4096;    // planes stride (u16 elems)
    const long long sYt = (long long)CC * DD;      // 524288 (u16 elems)
    const long long sL2t = (long long)HWW * DD;    // 262144 (u16 elems)

    // G1: Yv = relu(sc*(W_v2l . v2l^T) + b)   [D,C] per batch
    mfma_gemm<128, 0, 0, 1><<<dim3(CC / 128, 2, BB), 256, 0, stream>>>(
        w_v2l, nullptr, 0, HWW, v2l, nullptr, sX, HWW, Yv, sY, CC, HWW, g_v2l, b_v2l);

    // row-normalize Yv over C, rewrite in place as planes (lda=4096)
    rownorm_split_k<<<dim3(DD, BB), 256, 0, stream>>>(Yv);

    // G2: Yl
    mfma_gemm<128, 0, 0, 1><<<dim3(CC / 128, 2, BB), 256, 0, stream>>>(
        w_l2v, nullptr, 0, HWW, l2v, nullptr, sX, HWW, Yl, sY, CC, HWW, g_l2v, b_l2v);

    // column inv-norms of Yl over D; Ylt = split(transpose(Yl) * rsc) [C,D]
    colnorm_k<<<dim3(CC / 256, BB), 256, 0, stream>>>(Yl, rsc);
    trans_split_k<1><<<dim3(CC / 32, DD / 32, BB), 256, 0, stream>>>(
        Yl, DD, CC, rsc, YltHi, YltLo);

    // G3: latent = Yvn . B3^T   (B3 = ileave reinterpret of v2l)  [D,HW]
    mfma_gemm<64, 1, 2, 0><<<dim3(HWW / 64, 2, BB), 256, 0, stream>>>(
        (const u16*)Yv, (const u16*)Yv + CC, sYp, 4096,
        v2l, nullptr, sX, HWW, latent, sL, HWW, CC, nullptr, nullptr);

    // gram = latent . latent^T (fp32 NT)
    gemm_k<64, 64, 16, 4, 4, 0><<<dim3(4, 4, BB), 256, 0, stream>>>(
        latent, sL, HWW, latent, sL, HWW, gram, sG, DD, HWW);

    // softmax(normalized gram)
    latnorm_k<<<dim3(BB * DD / 256), 256, 0, stream>>>(gram, rs);
    softmax_k<<<dim3(DD, BB), 256, 0, stream>>>(gram, rs);

    // lat2 = aff . latent (fp32 NN)
    gemm_k<128, 128, 16, 8, 8, 1><<<dim3(8, 2, BB), 256, 0, stream>>>(
        gram, sG, DD, latent, sL, HWW, lat2, sL, HWW, DD);

    // lat2t = split(transpose(lat2)) [HW,D]
    trans_split_k<0><<<dim3(HWW / 32, DD / 32, BB), 256, 0, stream>>>(
        lat2, DD, HWW, nullptr, l2tHi, l2tLo);

    // G6: out = Ylt . lat2t^T  [C,HW]
    mfma_gemm<128, 1, 1, 0><<<dim3(HWW / 128, CC / 128, BB), 256, 0, stream>>>(
        YltHi, YltLo, sYt, DD, l2tHi, l2tLo, sL2t, DD, out, sX, HWW, DD, nullptr, nullptr);
}

// Round 4
// 446.422 us; speedup vs baseline: 2.4197x; 1.0354x over previous
//
#include <hip/hip_runtime.h>
#include <hip/hip_bf16.h>

#define BB 16
#define CC 2048
#define HWW 1024
#define DD 256
#define BN_RSQRT 0.9999950000374997f

typedef short bf16x8 __attribute__((ext_vector_type(8)));
typedef float f32x4 __attribute__((ext_vector_type(4)));
typedef unsigned short u16x8 __attribute__((ext_vector_type(8)));
typedef unsigned short u16;

// ---- bf16 split helpers (RNE) ----
__device__ __forceinline__ unsigned short f2bf(float x) {
    unsigned u = __builtin_bit_cast(unsigned, x);
    unsigned r = u + 0x7FFFu + ((u >> 16) & 1u);
    return (unsigned short)(r >> 16);
}
__device__ __forceinline__ float bf2f(unsigned short h) {
    unsigned u = ((unsigned)h) << 16;
    return __builtin_bit_cast(float, u);
}
__device__ __forceinline__ void split2(float x, unsigned short& hi, unsigned short& lo) {
    hi = f2bf(x);
    lo = f2bf(x - bf2f(hi));
}
__device__ __forceinline__ void split16(const float* v, u16x8& h0, u16x8& h1,
                                        u16x8& l0, u16x8& l1) {
    #pragma unroll
    for (int j = 0; j < 8; ++j) { unsigned short hh, ll; split2(v[j], hh, ll); h0[j] = hh; l0[j] = ll; }
    #pragma unroll
    for (int j = 0; j < 8; ++j) { unsigned short hh, ll; split2(v[8 + j], hh, ll); h1[j] = hh; l1[j] = ll; }
}

struct RegsA { float4 f[4]; u16x8 h[2]; u16x8 l[2]; };
struct RegsB { float4 f[4]; u16x8 h[2]; u16x8 l[2]; };

// ---------------------------------------------------------------------------
// split fp32 -> hi/lo bf16 planes (used for weights only)
// ---------------------------------------------------------------------------
__global__ __launch_bounds__(256) void split_k(const float* __restrict__ in,
                                               u16* __restrict__ hi, u16* __restrict__ lo,
                                               long long n8) {
    long long i = (long long)blockIdx.x * 256 + threadIdx.x;
    if (i >= n8) return;
    const float4* p = (const float4*)in + i * 2;
    float4 a = p[0], b = p[1];
    float xs[8] = {a.x, a.y, a.z, a.w, b.x, b.y, b.z, b.w};
    u16x8 h, l;
    #pragma unroll
    for (int j = 0; j < 8; ++j) { unsigned short hh, ll; split2(xs[j], hh, ll); h[j] = hh; l[j] = ll; }
    *(u16x8*)(hi + i * 8) = h;
    *(u16x8*)(lo + i * 8) = l;
}

// ---------------------------------------------------------------------------
// Unified split-bf16 MFMA GEMM, NT form: C[M,N] = sum_k A[m][k]*B[n][k]
// BM=128, BK=32, 4 waves, dbuf LDS, reg-staged, RAW barrier (lgkmcnt(0) only —
// no vmcnt drain: reg-destined global loads stay in flight across barriers).
// AFMT: 1 = bf16 hi/lo planes (Ap,Ap2)
// BFMT: 0 = fp32 row-major [n][k] (split on the fly)
//       1 = bf16 hi/lo planes
//       2 = fp32 ileave: B[h][2q+r] = Bp[(r*1024+h)][q]  (ldb fixed = HWW)
// EPI : 0 = fp32 store; 1 = relu(g*BN_RSQRT*x+b) fp32 store;
//       2 = split-planes store (Cp,Cp2) + transposed planes (Ct,Ct2, ldct);
//       3 = split-planes store (Cp,Cp2) only
// ---------------------------------------------------------------------------
template <int BN_, int AFMT, int BFMT, int EPI>
__global__ __launch_bounds__(256) void mfma_gemm(
    const void* __restrict__ Ap, const void* __restrict__ Ap2, long long aB, int lda,
    const void* __restrict__ Bp, const void* __restrict__ Bp2, long long bB, int ldb,
    void* __restrict__ Cp, void* __restrict__ Cp2,
    void* __restrict__ Ct, void* __restrict__ Ct2,
    long long cB, int ldc, int ldct,
    int K, const float* __restrict__ gp, const float* __restrict__ bpb)
{
    constexpr int NJ   = BN_ / 32;
    constexpr int BNB  = BN_ * 64;          // bytes per B plane
    constexpr int BUFB = 16384 + BN_ * 128;
    __shared__ __attribute__((aligned(16))) char smem[2][BUFB];

    // bijective XCD-chunk swizzle (all grids divisible by 8)
    const int gx = gridDim.x, gy = gridDim.y;
    int nwg = gx * gy * gridDim.z;
    int id = blockIdx.x + gx * (blockIdx.y + gy * blockIdx.z);
    int chunk = nwg >> 3;
    int nid = (id & 7) * chunk + (id >> 3);
    int bx = nid % gx;
    int tmp = nid / gx;
    int by = tmp % gy;
    int bz = tmp / gy;

    const int t  = threadIdx.x;
    const int n0 = bx * BN_;
    const int m0 = by * 128;

    // staging coords
    const int ar = t >> 1, ag = t & 1;
    const int af = (ar >> 1) & 3;
    const int as0 = (2 * ag) ^ af, as1 = (2 * ag + 1) ^ af;
    const bool bact = (BN_ == 128) || (t < 2 * BN_);
    const int br = (t >> 1) & (BN_ - 1), bg = t & 1;
    const int bf = (br >> 1) & 3;
    const int bs0 = (2 * bg) ^ bf, bs1 = (2 * bg + 1) ^ bf;

    // fragment coords
    const int l  = t & 63, w = t >> 6;
    const int wr = w >> 1, wc = w & 1;
    const int rl = l & 15, kq = l >> 4;
    const int sw = kq ^ ((rl >> 1) & 3);
    const int aoff = (wr * 64 + rl) * 64 + sw * 16;
    const int boff = (wc * (BN_ / 2) + rl) * 64 + sw * 16;

    const u16*   Ahp = (const u16*)Ap  + (long long)bz * aB;
    const u16*   Alp = (const u16*)Ap2 + (long long)bz * aB;
    const float* Bfp = (const float*)Bp + (long long)bz * bB;
    const u16*   Bhp = (const u16*)Bp  + (long long)bz * bB;
    const u16*   Blp = (const u16*)Bp2 + (long long)bz * bB;

    auto loadA = [&](int k0, RegsA& ra) {
        const u16* ph = Ahp + (long long)(m0 + ar) * lda + k0 + ag * 16;
        const u16* pl = Alp + (long long)(m0 + ar) * lda + k0 + ag * 16;
        ra.h[0] = *(const u16x8*)(ph);
        ra.h[1] = *(const u16x8*)(ph + 8);
        ra.l[0] = *(const u16x8*)(pl);
        ra.l[1] = *(const u16x8*)(pl + 8);
    };
    auto loadB = [&](int k0, RegsB& rb) {
        if (!bact) return;
        if constexpr (BFMT == 0) {
            const float* p = Bfp + (long long)(n0 + br) * ldb + k0 + bg * 16;
            rb.f[0] = *(const float4*)(p);
            rb.f[1] = *(const float4*)(p + 4);
            rb.f[2] = *(const float4*)(p + 8);
            rb.f[3] = *(const float4*)(p + 12);
        } else if constexpr (BFMT == 1) {
            const u16* ph = Bhp + (long long)(n0 + br) * ldb + k0 + bg * 16;
            const u16* pl = Blp + (long long)(n0 + br) * ldb + k0 + bg * 16;
            rb.h[0] = *(const u16x8*)(ph);
            rb.h[1] = *(const u16x8*)(ph + 8);
            rb.l[0] = *(const u16x8*)(pl);
            rb.l[1] = *(const u16x8*)(pl + 8);
        } else {
            int q0 = (k0 >> 1) + bg * 8;
            const float* p0 = Bfp + (long long)(n0 + br) * HWW + q0;
            const float* p1 = p0 + (long long)HWW * HWW;
            rb.f[0] = *(const float4*)(p0);
            rb.f[1] = *(const float4*)(p0 + 4);
            rb.f[2] = *(const float4*)(p1);
            rb.f[3] = *(const float4*)(p1 + 4);
        }
    };
    auto stageWrite = [&](char* sb, RegsA& ra, RegsB& rb) {
        *(u16x8*)(sb + ar * 64 + as0 * 16) = ra.h[0];
        *(u16x8*)(sb + ar * 64 + as1 * 16) = ra.h[1];
        *(u16x8*)(sb + 8192 + ar * 64 + as0 * 16) = ra.l[0];
        *(u16x8*)(sb + 8192 + ar * 64 + as1 * 16) = ra.l[1];
        if (bact) {
            char* sB = sb + 16384;
            if constexpr (BFMT == 1) {
                *(u16x8*)(sB + br * 64 + bs0 * 16) = rb.h[0];
                *(u16x8*)(sB + br * 64 + bs1 * 16) = rb.h[1];
                *(u16x8*)(sB + BNB + br * 64 + bs0 * 16) = rb.l[0];
                *(u16x8*)(sB + BNB + br * 64 + bs1 * 16) = rb.l[1];
            } else {
                float v[16];
                if constexpr (BFMT == 0) {
                    float vv[16] = {rb.f[0].x, rb.f[0].y, rb.f[0].z, rb.f[0].w,
                                    rb.f[1].x, rb.f[1].y, rb.f[1].z, rb.f[1].w,
                                    rb.f[2].x, rb.f[2].y, rb.f[2].z, rb.f[2].w,
                                    rb.f[3].x, rb.f[3].y, rb.f[3].z, rb.f[3].w};
                    #pragma unroll
                    for (int j = 0; j < 16; ++j) v[j] = vv[j];
                } else {
                    float vv[16] = {rb.f[0].x, rb.f[2].x, rb.f[0].y, rb.f[2].y,
                                    rb.f[0].z, rb.f[2].z, rb.f[0].w, rb.f[2].w,
                                    rb.f[1].x, rb.f[3].x, rb.f[1].y, rb.f[3].y,
                                    rb.f[1].z, rb.f[3].z, rb.f[1].w, rb.f[3].w};
                    #pragma unroll
                    for (int j = 0; j < 16; ++j) v[j] = vv[j];
                }
                u16x8 h0, h1, l0, l1;
                split16(v, h0, h1, l0, l1);
                *(u16x8*)(sB + br * 64 + bs0 * 16) = h0;
                *(u16x8*)(sB + br * 64 + bs1 * 16) = h1;
                *(u16x8*)(sB + BNB + br * 64 + bs0 * 16) = l0;
                *(u16x8*)(sB + BNB + br * 64 + bs1 * 16) = l1;
            }
        }
    };

    f32x4 acc[4][NJ];
    #pragma unroll
    for (int i = 0; i < 4; ++i)
        #pragma unroll
        for (int j = 0; j < NJ; ++j)
            acc[i][j] = (f32x4){0.f, 0.f, 0.f, 0.f};

    RegsA a0, a1;
    RegsB b0, b1;
    const int NIT = K >> 5;

    // prologue: data0 -> (a0,b0) -> buf0; data1 -> (a1,b1)
    loadA(0, a0); loadB(0, b0);
    stageWrite(smem[0], a0, b0);
    loadA(32, a1); loadB(32, b1);
    asm volatile("s_waitcnt lgkmcnt(0)" ::: "memory");
    __builtin_amdgcn_s_barrier();

    auto step = [&](int it, char* sb, char* sn, RegsA& pa, RegsB& pb,
                    RegsA& qa, RegsB& qb) {
        // frag reads of current buffer
        bf16x8 fah[4], fal[4], fbh[NJ], fbl[NJ];
        #pragma unroll
        for (int i = 0; i < 4; ++i) {
            fah[i] = *(const bf16x8*)(sb + aoff + i * 1024);
            fal[i] = *(const bf16x8*)(sb + 8192 + aoff + i * 1024);
        }
        #pragma unroll
        for (int j = 0; j < NJ; ++j) {
            fbh[j] = *(const bf16x8*)(sb + 16384 + boff + j * 1024);
            fbl[j] = *(const bf16x8*)(sb + 16384 + BNB + boff + j * 1024);
        }
        // stage next buffer from regs loaded a full iteration ago
        if (it + 1 < NIT) stageWrite(sn, pa, pb);
        // issue loads two steps ahead into the freed set
        if (it + 2 < NIT) { loadA((it + 2) << 5, qa); loadB((it + 2) << 5, qb); }
        // MFMA
        #pragma unroll
        for (int i = 0; i < 4; ++i)
            #pragma unroll
            for (int j = 0; j < NJ; ++j) {
                acc[i][j] = __builtin_amdgcn_mfma_f32_16x16x32_bf16(fal[i], fbh[j], acc[i][j], 0, 0, 0);
                acc[i][j] = __builtin_amdgcn_mfma_f32_16x16x32_bf16(fah[i], fbl[j], acc[i][j], 0, 0, 0);
                acc[i][j] = __builtin_amdgcn_mfma_f32_16x16x32_bf16(fah[i], fbh[j], acc[i][j], 0, 0, 0);
            }
        // raw barrier: own LDS ops drained; vmem loads stay in flight
        asm volatile("s_waitcnt lgkmcnt(0)" ::: "memory");
        __builtin_amdgcn_s_barrier();
    };

    for (int it = 0; it < NIT; it += 2) {
        step(it,     smem[0], smem[1], a1, b1, a0, b0);
        step(it + 1, smem[1], smem[0], a0, b0, a1, b1);
    }

    // epilogue
    #pragma unroll
    for (int i = 0; i < 4; ++i) {
        #pragma unroll
        for (int r = 0; r < 4; ++r) {
            int row = m0 + wr * 64 + i * 16 + kq * 4 + r;
            float sc = 1.0f, bi = 0.0f;
            if (EPI == 1) { sc = gp[row] * BN_RSQRT; bi = bpb[row]; }
            #pragma unroll
            for (int j = 0; j < NJ; ++j) {
                int col = n0 + wc * (BN_ / 2) + j * 16 + rl;
                float v = acc[i][j][r];
                if constexpr (EPI == 0) {
                    ((float*)Cp + (long long)bz * cB)[(long long)row * ldc + col] = v;
                } else if constexpr (EPI == 1) {
                    v = fmaxf(fmaf(v, sc, bi), 0.0f);
                    ((float*)Cp + (long long)bz * cB)[(long long)row * ldc + col] = v;
                } else {
                    unsigned short hh, ll; split2(v, hh, ll);
                    ((u16*)Cp  + (long long)bz * cB)[(long long)row * ldc + col] = hh;
                    ((u16*)Cp2 + (long long)bz * cB)[(long long)row * ldc + col] = ll;
                    if constexpr (EPI == 2) {
                        ((u16*)Ct  + (long long)bz * cB)[(long long)col * ldct + row] = hh;
                        ((u16*)Ct2 + (long long)bz * cB)[(long long)col * ldct + row] = ll;
                    }
                }
            }
        }
    }
}

// ---------------------------------------------------------------------------
// Row L2-norm over C of Y[B][D][C] fp32 -> in-place split planes (lda=4096)
// ---------------------------------------------------------------------------
__global__ __launch_bounds__(256) void rownorm_split_k(float* __restrict__ Y) {
    int d = blockIdx.x, b = blockIdx.y, t = threadIdx.x;
    float* row = Y + ((long long)b * DD + d) * CC;
    float4 v0 = ((const float4*)row)[2 * t];
    float4 v1 = ((const float4*)row)[2 * t + 1];
    float s = v0.x * v0.x + v0.y * v0.y + v0.z * v0.z + v0.w * v0.w
            + v1.x * v1.x + v1.y * v1.y + v1.z * v1.z + v1.w * v1.w;
    for (int off = 32; off > 0; off >>= 1) s += __shfl_down(s, off, 64);
    __shared__ float wsum[4];
    __shared__ float ivs;
    int lane = t & 63, w = t >> 6;
    if (lane == 0) wsum[w] = s;
    __syncthreads();
    if (t == 0) ivs = 1.0f / fmaxf(sqrtf(wsum[0] + wsum[1] + wsum[2] + wsum[3]), 1e-12f);
    __syncthreads();
    float iv = ivs;
    float xs[8] = {v0.x * iv, v0.y * iv, v0.z * iv, v0.w * iv,
                   v1.x * iv, v1.y * iv, v1.z * iv, v1.w * iv};
    u16x8 h, l2;
    #pragma unroll
    for (int j = 0; j < 8; ++j) { unsigned short hh, ll; split2(xs[j], hh, ll); h[j] = hh; l2[j] = ll; }
    u16* hi = (u16*)row;
    *(u16x8*)(hi + t * 8) = h;
    *(u16x8*)(hi + CC + t * 8) = l2;
}

// ---------------------------------------------------------------------------
__global__ __launch_bounds__(256) void colnorm_k(const float* __restrict__ Yl,
                                                 float* __restrict__ rsc) {
    int b = blockIdx.y;
    int c = blockIdx.x * 256 + threadIdx.x;
    const float* base = Yl + (long long)b * DD * CC + c;
    float s = 0.0f;
    for (int d = 0; d < DD; ++d) { float v = base[(long long)d * CC]; s += v * v; }
    rsc[(long long)b * CC + c] = 1.0f / fmaxf(sqrtf(s), 1e-12f);
}

// ---------------------------------------------------------------------------
// transpose + column-scale + split: Yl[B][D][C] -> Ylt planes [B][C][D]
// ---------------------------------------------------------------------------
__global__ __launch_bounds__(256) void trans_split_k(const float* __restrict__ in,
                                                     const float* __restrict__ scale,
                                                     u16* __restrict__ hi, u16* __restrict__ lo) {
    __shared__ float tile[32][33];
    int s0 = blockIdx.x * 32, r0 = blockIdx.y * 32, b = blockIdx.z;
    const float* inb = in + (long long)b * DD * CC;
    int tx = threadIdx.x & 31, ty = threadIdx.x >> 5;
    for (int i = ty; i < 32; i += 8)
        tile[i][tx] = inb[(long long)(r0 + i) * CC + s0 + tx];
    __syncthreads();
    for (int i = ty; i < 32; i += 8) {
        float v = tile[tx][i] * scale[(long long)b * CC + s0 + i];
        unsigned short hh, ll; split2(v, hh, ll);
        long long o = (long long)b * DD * CC + (long long)(s0 + i) * DD + r0 + tx;
        hi[o] = hh; lo[o] = ll;
    }
}

// ---------------------------------------------------------------------------
__global__ __launch_bounds__(256) void latnorm_k(const float* __restrict__ G,
                                                 float* __restrict__ rs) {
    int i = blockIdx.x * 256 + threadIdx.x;
    int b = i >> 8, d = i & 255;
    float v = G[((long long)b * DD + d) * DD + d];
    rs[i] = 1.0f / fmaxf(sqrtf(v), 1e-12f);
}

// softmax over gram rows -> aff hi/lo planes
__global__ __launch_bounds__(256) void softmax_k(const float* __restrict__ G,
                                                 const float* __restrict__ rs,
                                                 u16* __restrict__ affHi,
                                                 u16* __restrict__ affLo) {
    int d = blockIdx.x, b = blockIdx.y;
    const float* row = G + ((long long)b * DD + d) * DD;
    const float* rsb = rs + (long long)b * DD;
    int t = threadIdx.x;
    float lg = row[t] * rsb[d] * rsb[t];

    float m = lg;
    for (int off = 32; off > 0; off >>= 1) m = fmaxf(m, __shfl_down(m, off, 64));
    __shared__ float wsm[4];
    __shared__ float bm, bs;
    int lane = t & 63, w = t >> 6;
    if (lane == 0) wsm[w] = m;
    __syncthreads();
    if (t == 0) bm = fmaxf(fmaxf(wsm[0], wsm[1]), fmaxf(wsm[2], wsm[3]));
    __syncthreads();
    float e = expf(lg - bm);
    float s = e;
    for (int off = 32; off > 0; off >>= 1) s += __shfl_down(s, off, 64);
    if (lane == 0) wsm[w] = s;
    __syncthreads();
    if (t == 0) bs = wsm[0] + wsm[1] + wsm[2] + wsm[3];
    __syncthreads();
    float v = e / bs;
    unsigned short hh, ll; split2(v, hh, ll);
    long long o = ((long long)b * DD + d) * DD + t;
    affHi[o] = hh; affLo[o] = ll;
}

// ---------------------------------------------------------------------------
extern "C" void kernel_launch(void* const* d_in, const int* in_sizes, int n_in,
                              void* d_out, int out_size, void* d_ws, size_t ws_size,
                              hipStream_t stream) {
    const float* v2l   = (const float*)d_in[0];
    const float* l2v   = (const float*)d_in[1];
    const float* w_v2l = (const float*)d_in[2];
    const float* g_v2l = (const float*)d_in[3];
    const float* b_v2l = (const float*)d_in[4];
    const float* w_l2v = (const float*)d_in[5];
    const float* g_l2v = (const float*)d_in[6];
    const float* b_l2v = (const float*)d_in[7];
    float* out = (float*)d_out;

    char* W = (char*)d_ws;
    float* Yv     = (float*)(W + 0);            // 32MB fp32 -> in-place planes
    float* Yl     = (float*)(W + 33554432);     // 32MB
    u16*   YltHi  = (u16*)(W + 67108864);       // 16MB
    u16*   YltLo  = (u16*)(W + 83886080);       // 16MB
    u16*   latHi  = (u16*)(W + 100663296);      //  8MB
    u16*   latLo  = (u16*)(W + 109051904);      //  8MB
    u16*   latTHi = (u16*)(W + 117440512);      //  8MB
    u16*   latTLo = (u16*)(W + 125829120);      //  8MB
    u16*   l2tHi  = (u16*)(W + 134217728);      //  8MB
    u16*   l2tLo  = (u16*)(W + 142606336);      //  8MB
    float* gram   = (float*)(W + 150994944);    //  4MB
    float* rs     = (float*)(W + 155189248);
    float* rsc    = (float*)(W + 155205632);
    u16*   affHi  = (u16*)(W + 155336704);      //  2MB
    u16*   affLo  = (u16*)(W + 157433856);      //  2MB
    u16*   WvHi   = (u16*)(W + 159531008);      //  512KB each
    u16*   WvLo   = WvHi + 262144;
    u16*   WlHi   = WvLo + 262144;
    u16*   WlLo   = WlHi + 262144;

    const long long sY   = (long long)DD * CC;     // 524288
    const long long sL   = (long long)DD * HWW;    // 262144
    const long long sG   = (long long)DD * DD;     // 65536
    const long long sX   = (long long)CC * HWW;    // 2097152
    const long long sYp  = (long long)DD * 4096;   // in-place plane stride

    // weights -> planes (once per call, tiny)
    split_k<<<128, 256, 0, stream>>>(w_v2l, WvHi, WvLo, 32768);
    split_k<<<128, 256, 0, stream>>>(w_l2v, WlHi, WlLo, 32768);

    // G1: Yv = relu(sc*(Wv . v2l^T)+b)  [D,C]
    mfma_gemm<128, 1, 0, 1><<<dim3(16, 2, BB), 256, 0, stream>>>(
        WvHi, WvLo, 0, HWW, v2l, nullptr, sX, HWW,
        Yv, nullptr, nullptr, nullptr, sY, CC, 0, HWW, g_v2l, b_v2l);

    rownorm_split_k<<<dim3(DD, BB), 256, 0, stream>>>(Yv);

    // G2: Yl
    mfma_gemm<128, 1, 0, 1><<<dim3(16, 2, BB), 256, 0, stream>>>(
        WlHi, WlLo, 0, HWW, l2v, nullptr, sX, HWW,
        Yl, nullptr, nullptr, nullptr, sY, CC, 0, HWW, g_l2v, b_l2v);

    colnorm_k<<<dim3(CC / 256, BB), 256, 0, stream>>>(Yl, rsc);
    trans_split_k<<<dim3(CC / 32, DD / 32, BB), 256, 0, stream>>>(Yl, rsc, YltHi, YltLo);

    // G3: latent = Yvn . B3^T  [D,HW]; emits latent planes + latentT planes
    mfma_gemm<64, 1, 2, 2><<<dim3(HWW / 64, 2, BB), 256, 0, stream>>>(
        (const u16*)Yv, (const u16*)Yv + CC, sYp, 4096, v2l, nullptr, sX, HWW,
        latHi, latLo, latTHi, latTLo, sL, HWW, DD, CC, nullptr, nullptr);

    // gram = latent . latent^T  (plane MFMA, fp32 out)
    mfma_gemm<64, 1, 1, 0><<<dim3(4, 2, BB), 256, 0, stream>>>(
        latHi, latLo, sL, HWW, latHi, latLo, sL, HWW,
        gram, nullptr, nullptr, nullptr, sG, DD, 0, HWW, nullptr, nullptr);

    latnorm_k<<<dim3(BB * DD / 256), 256, 0, stream>>>(gram, rs);
    softmax_k<<<dim3(DD, BB), 256, 0, stream>>>(gram, rs, affHi, affLo);

    // lat2t = latentT . aff^T  [HW,D] -> planes (l2t)
    mfma_gemm<128, 1, 1, 3><<<dim3(2, HWW / 128, BB), 256, 0, stream>>>(
        latTHi, latTLo, sL, DD, affHi, affLo, sG, DD,
        l2tHi, l2tLo, nullptr, nullptr, sL, DD, 0, DD, nullptr, nullptr);

    // G6: out = Ylt . l2t^T  [C,HW]
    mfma_gemm<128, 1, 1, 0><<<dim3(HWW / 128, CC / 128, BB), 256, 0, stream>>>(
        YltHi, YltLo, sY, DD, l2tHi, l2tLo, sL, DD,
        out, nullptr, nullptr, nullptr, sX, HWW, 0, DD, nullptr, nullptr);
}

// Round 5
// 403.708 us; speedup vs baseline: 2.6757x; 1.1058x over previous
//
#include <hip/hip_runtime.h>
#include <hip/hip_bf16.h>

#define BB 16
#define CC 2048
#define HWW 1024
#define DD 256
#define BN_RSQRT 0.9999950000374997f

typedef short bf16x8 __attribute__((ext_vector_type(8)));
typedef float f32x4 __attribute__((ext_vector_type(4)));
typedef unsigned short u16x8 __attribute__((ext_vector_type(8)));
typedef unsigned short u16;

// ---- bf16 split helpers (RNE) ----
__device__ __forceinline__ unsigned short f2bf(float x) {
    unsigned u = __builtin_bit_cast(unsigned, x);
    unsigned r = u + 0x7FFFu + ((u >> 16) & 1u);
    return (unsigned short)(r >> 16);
}
__device__ __forceinline__ float bf2f(unsigned short h) {
    unsigned u = ((unsigned)h) << 16;
    return __builtin_bit_cast(float, u);
}
__device__ __forceinline__ void split2(float x, unsigned short& hi, unsigned short& lo) {
    hi = f2bf(x);
    lo = f2bf(x - bf2f(hi));
}
__device__ __forceinline__ void split16(const float* v, u16x8& h0, u16x8& h1,
                                        u16x8& l0, u16x8& l1) {
    #pragma unroll
    for (int j = 0; j < 8; ++j) { unsigned short hh, ll; split2(v[j], hh, ll); h0[j] = hh; l0[j] = ll; }
    #pragma unroll
    for (int j = 0; j < 8; ++j) { unsigned short hh, ll; split2(v[8 + j], hh, ll); h1[j] = hh; l1[j] = ll; }
}

struct RegsA { float4 f[4]; u16x8 h[2]; u16x8 l[2]; };
struct RegsB { float4 f[4]; u16x8 h[2]; u16x8 l[2]; };

// ---------------------------------------------------------------------------
// split fp32 -> hi/lo bf16 planes (weights only)
// ---------------------------------------------------------------------------
__global__ __launch_bounds__(256) void split_k(const float* __restrict__ in,
                                               u16* __restrict__ hi, u16* __restrict__ lo,
                                               long long n8) {
    long long i = (long long)blockIdx.x * 256 + threadIdx.x;
    if (i >= n8) return;
    const float4* p = (const float4*)in + i * 2;
    float4 a = p[0], b = p[1];
    float xs[8] = {a.x, a.y, a.z, a.w, b.x, b.y, b.z, b.w};
    u16x8 h, l;
    #pragma unroll
    for (int j = 0; j < 8; ++j) { unsigned short hh, ll; split2(xs[j], hh, ll); h[j] = hh; l[j] = ll; }
    *(u16x8*)(hi + i * 8) = h;
    *(u16x8*)(lo + i * 8) = l;
}

// ---------------------------------------------------------------------------
// 8-phase-style split-bf16 MFMA GEMM (NT): C[M,N] = sum_k A[m][k]*B[n][k]
// 256x256 tile, BK=32, 8 waves (512 thr), dbuf LDS 2x64KB, reg-staged,
// 4 sub-phases per K-tile: {12 ds_read frags | staging slice | 24 MFMA} each,
// setprio around MFMA, raw phase barriers, counted-wait only at tile boundary.
// A is always bf16 hi/lo planes. BFMT: 0 = fp32 (split on the fly), 1 = planes.
// EPI: 0 = fp32 store, 1 = relu(g*BN_RSQRT*x + b).
// FUSE2: gridDim.z = 32, z>=16 selects the second operand set (op 1).
// ---------------------------------------------------------------------------
template <int BFMT, int EPI, int FUSE2>
__global__ __launch_bounds__(512, 2) void gemm8(
    const u16* __restrict__ Ah0, const u16* __restrict__ Al0,
    const u16* __restrict__ Ah1, const u16* __restrict__ Al1,
    long long aB, int lda,
    const void* __restrict__ B0a, const void* __restrict__ B0b,
    const void* __restrict__ B1a, const void* __restrict__ B1b,
    long long bB, int ldb,
    float* __restrict__ C0, float* __restrict__ C1, long long cB, int ldc,
    int K,
    const float* __restrict__ g0, const float* __restrict__ bb0,
    const float* __restrict__ g1, const float* __restrict__ bb1)
{
    __shared__ __attribute__((aligned(16))) char smem[2][65536];

    // bijective XCD-chunk swizzle (nwg % 8 == 0 for all our grids)
    const int gx = gridDim.x, gy = gridDim.y;
    int nwg = gx * gy * gridDim.z;
    int id = blockIdx.x + gx * (blockIdx.y + gy * blockIdx.z);
    int chunk = nwg >> 3;
    int nid = (id & 7) * chunk + (id >> 3);
    int bx = nid % gx;
    int tmp = nid / gx;
    int by = tmp % gy;
    int bz = tmp / gy;

    const int t = threadIdx.x;
    const int n0 = bx * 256, m0 = by * 256;
    const int op = FUSE2 ? (bz >> 4) : 0;
    const int batch = FUSE2 ? (bz & 15) : bz;

    const u16* Ahp = (op ? Ah1 : Ah0) + (long long)batch * aB;
    const u16* Alp = (op ? Al1 : Al0) + (long long)batch * aB;
    const float* Bfp = nullptr;
    const u16* Bhp = nullptr;
    const u16* Blp = nullptr;
    if constexpr (BFMT == 0) {
        Bfp = (const float*)(op ? B1a : B0a) + (long long)batch * bB;
    } else {
        Bhp = (const u16*)(op ? B1a : B0a) + (long long)batch * bB;
        Blp = (const u16*)(op ? B1b : B0b) + (long long)batch * bB;
    }
    float* Cb = (op ? C1 : C0) + (long long)batch * cB;
    const float* gp = op ? g1 : g0;
    const float* bp = op ? bb1 : bb0;

    // staging coords: thread t -> row ar (0..255), k-half ag, XOR'd 16B slots
    const int ar = t >> 1, ag = t & 1;
    const int af = (ar >> 1) & 3;
    const int as0 = ((2 * ag) ^ af) * 16, as1 = ((2 * ag + 1) ^ af) * 16;

    // fragment coords: 8 waves -> (wr 0..1, wc 0..3); per-wave out 128x64
    const int l = t & 63, w = t >> 6;
    const int wr = w >> 2, wc = w & 3;
    const int rl = l & 15, kq = l >> 4;
    const int sw16 = (kq ^ ((rl >> 1) & 3)) * 16;

    f32x4 acc[8][4];
    #pragma unroll
    for (int i = 0; i < 8; ++i)
        #pragma unroll
        for (int j = 0; j < 4; ++j)
            acc[i][j] = (f32x4){0.f, 0.f, 0.f, 0.f};

    // stage registers (one K-tile in flight)
    u16x8 rah0, rah1, ral0, ral1;
    u16x8 rbh0, rbh1, rbl0, rbl1;
    float4 rbf0, rbf1, rbf2, rbf3;

    auto loadAB = [&](int k0) {
        const u16* pa = Ahp + (long long)(m0 + ar) * lda + k0 + ag * 16;
        rah0 = *(const u16x8*)pa;
        rah1 = *(const u16x8*)(pa + 8);
        const u16* pl = Alp + (long long)(m0 + ar) * lda + k0 + ag * 16;
        ral0 = *(const u16x8*)pl;
        ral1 = *(const u16x8*)(pl + 8);
        if constexpr (BFMT == 0) {
            const float* pb = Bfp + (long long)(n0 + ar) * ldb + k0 + ag * 16;
            rbf0 = *(const float4*)pb;
            rbf1 = *(const float4*)(pb + 4);
            rbf2 = *(const float4*)(pb + 8);
            rbf3 = *(const float4*)(pb + 12);
        } else {
            const u16* pbh = Bhp + (long long)(n0 + ar) * ldb + k0 + ag * 16;
            rbh0 = *(const u16x8*)pbh;
            rbh1 = *(const u16x8*)(pbh + 8);
            const u16* pbl = Blp + (long long)(n0 + ar) * ldb + k0 + ag * 16;
            rbl0 = *(const u16x8*)pbl;
            rbl1 = *(const u16x8*)(pbl + 8);
        }
    };
    auto writeA = [&](char* sn) {
        char* base = sn + ar * 64;
        *(u16x8*)(base + as0) = rah0;
        *(u16x8*)(base + as1) = rah1;
        *(u16x8*)(base + 16384 + as0) = ral0;
        *(u16x8*)(base + 16384 + as1) = ral1;
    };
    auto writeB = [&](char* sn) {
        char* base = sn + 32768 + ar * 64;
        if constexpr (BFMT == 0) {
            float v[16] = {rbf0.x, rbf0.y, rbf0.z, rbf0.w,
                           rbf1.x, rbf1.y, rbf1.z, rbf1.w,
                           rbf2.x, rbf2.y, rbf2.z, rbf2.w,
                           rbf3.x, rbf3.y, rbf3.z, rbf3.w};
            u16x8 h0, h1, l0, l1;
            split16(v, h0, h1, l0, l1);
            *(u16x8*)(base + as0) = h0;
            *(u16x8*)(base + as1) = h1;
            *(u16x8*)(base + 16384 + as0) = l0;
            *(u16x8*)(base + 16384 + as1) = l1;
        } else {
            *(u16x8*)(base + as0) = rbh0;
            *(u16x8*)(base + as1) = rbh1;
            *(u16x8*)(base + 16384 + as0) = rbl0;
            *(u16x8*)(base + 16384 + as1) = rbl1;
        }
    };

#define PHASE(MH, NH, EXTRA) do {                                              \
    bf16x8 fah[4], fal[4], fbh[2], fbl[2];                                     \
    _Pragma("unroll")                                                          \
    for (int i2 = 0; i2 < 4; ++i2) {                                           \
        int off = (wr * 128 + ((MH) * 4 + i2) * 16 + rl) * 64 + sw16;          \
        fah[i2] = *(const bf16x8*)(sb + off);                                  \
        fal[i2] = *(const bf16x8*)(sb + 16384 + off);                          \
    }                                                                          \
    _Pragma("unroll")                                                          \
    for (int j2 = 0; j2 < 2; ++j2) {                                           \
        int off = (wc * 64 + ((NH) * 2 + j2) * 16 + rl) * 64 + sw16;           \
        fbh[j2] = *(const bf16x8*)(sb + 32768 + off);                          \
        fbl[j2] = *(const bf16x8*)(sb + 49152 + off);                          \
    }                                                                          \
    EXTRA;                                                                     \
    __builtin_amdgcn_s_setprio(1);                                             \
    _Pragma("unroll")                                                          \
    for (int i2 = 0; i2 < 4; ++i2)                                             \
        _Pragma("unroll")                                                      \
        for (int j2 = 0; j2 < 2; ++j2) {                                       \
            f32x4& a = acc[(MH) * 4 + i2][(NH) * 2 + j2];                      \
            a = __builtin_amdgcn_mfma_f32_16x16x32_bf16(fal[i2], fbh[j2], a, 0, 0, 0); \
            a = __builtin_amdgcn_mfma_f32_16x16x32_bf16(fah[i2], fbl[j2], a, 0, 0, 0); \
            a = __builtin_amdgcn_mfma_f32_16x16x32_bf16(fah[i2], fbh[j2], a, 0, 0, 0); \
        }                                                                      \
    __builtin_amdgcn_s_setprio(0);                                             \
} while (0)

    // prologue: tile 0 -> buf 0
    loadAB(0);
    writeA(smem[0]);
    writeB(smem[0]);
    asm volatile("s_waitcnt lgkmcnt(0)" ::: "memory");
    __builtin_amdgcn_s_barrier();

    const int NIT = K >> 5;
    for (int it = 0; it < NIT; ++it) {
        char* sb = smem[it & 1];
        char* sn = smem[(it + 1) & 1];
        const bool more = (it + 1) < NIT;
        const int k1 = (it + 1) << 5;

        PHASE(0, 0, { if (more) loadAB(k1); });
        asm volatile("" ::: "memory");
        __builtin_amdgcn_s_barrier();

        PHASE(0, 1, {});
        asm volatile("" ::: "memory");
        __builtin_amdgcn_s_barrier();

        PHASE(1, 0, { if (more) writeA(sn); });
        asm volatile("" ::: "memory");
        __builtin_amdgcn_s_barrier();

        PHASE(1, 1, { if (more) writeB(sn); });
        asm volatile("s_waitcnt lgkmcnt(0)" ::: "memory");
        __builtin_amdgcn_s_barrier();
    }
#undef PHASE

    // epilogue
    #pragma unroll
    for (int i = 0; i < 8; ++i) {
        #pragma unroll
        for (int r = 0; r < 4; ++r) {
            int row = m0 + wr * 128 + i * 16 + kq * 4 + r;
            float sc = 1.0f, bi = 0.0f;
            if (EPI == 1) { sc = gp[row] * BN_RSQRT; bi = bp[row]; }
            #pragma unroll
            for (int j = 0; j < 4; ++j) {
                int col = n0 + wc * 64 + j * 16 + rl;
                float v = acc[i][j][r];
                if (EPI == 1) v = fmaxf(fmaf(v, sc, bi), 0.0f);
                Cb[(long long)row * ldc + col] = v;
            }
        }
    }
}

// ---------------------------------------------------------------------------
// R4's 128-wide split-bf16 MFMA GEMM (kept for G3 / gram / lat2t)
// ---------------------------------------------------------------------------
template <int BN_, int AFMT, int BFMT, int EPI>
__global__ __launch_bounds__(256) void mfma_gemm(
    const void* __restrict__ Ap, const void* __restrict__ Ap2, long long aB, int lda,
    const void* __restrict__ Bp, const void* __restrict__ Bp2, long long bB, int ldb,
    void* __restrict__ Cp, void* __restrict__ Cp2,
    void* __restrict__ Ct, void* __restrict__ Ct2,
    long long cB, int ldc, int ldct,
    int K, const float* __restrict__ gp, const float* __restrict__ bpb)
{
    constexpr int NJ   = BN_ / 32;
    constexpr int BNB  = BN_ * 64;
    constexpr int BUFB = 16384 + BN_ * 128;
    __shared__ __attribute__((aligned(16))) char smem[2][BUFB];

    const int gx = gridDim.x, gy = gridDim.y;
    int nwg = gx * gy * gridDim.z;
    int id = blockIdx.x + gx * (blockIdx.y + gy * blockIdx.z);
    int chunk = nwg >> 3;
    int nid = (id & 7) * chunk + (id >> 3);
    int bx = nid % gx;
    int tmp = nid / gx;
    int by = tmp % gy;
    int bz = tmp / gy;

    const int t  = threadIdx.x;
    const int n0 = bx * BN_;
    const int m0 = by * 128;

    const int ar = t >> 1, ag = t & 1;
    const int af = (ar >> 1) & 3;
    const int as0 = (2 * ag) ^ af, as1 = (2 * ag + 1) ^ af;
    const bool bact = (BN_ == 128) || (t < 2 * BN_);
    const int br = (t >> 1) & (BN_ - 1), bg = t & 1;
    const int bf = (br >> 1) & 3;
    const int bs0 = (2 * bg) ^ bf, bs1 = (2 * bg + 1) ^ bf;

    const int l  = t & 63, w = t >> 6;
    const int wr = w >> 1, wc = w & 1;
    const int rl = l & 15, kq = l >> 4;
    const int sw = kq ^ ((rl >> 1) & 3);
    const int aoff = (wr * 64 + rl) * 64 + sw * 16;
    const int boff = (wc * (BN_ / 2) + rl) * 64 + sw * 16;

    const u16*   Ahp = (const u16*)Ap  + (long long)bz * aB;
    const u16*   Alp = (const u16*)Ap2 + (long long)bz * aB;
    const float* Bfp = (const float*)Bp + (long long)bz * bB;
    const u16*   Bhp = (const u16*)Bp  + (long long)bz * bB;
    const u16*   Blp = (const u16*)Bp2 + (long long)bz * bB;

    auto loadA = [&](int k0, RegsA& ra) {
        const u16* ph = Ahp + (long long)(m0 + ar) * lda + k0 + ag * 16;
        const u16* pl = Alp + (long long)(m0 + ar) * lda + k0 + ag * 16;
        ra.h[0] = *(const u16x8*)(ph);
        ra.h[1] = *(const u16x8*)(ph + 8);
        ra.l[0] = *(const u16x8*)(pl);
        ra.l[1] = *(const u16x8*)(pl + 8);
    };
    auto loadB = [&](int k0, RegsB& rb) {
        if (!bact) return;
        if constexpr (BFMT == 0) {
            const float* p = Bfp + (long long)(n0 + br) * ldb + k0 + bg * 16;
            rb.f[0] = *(const float4*)(p);
            rb.f[1] = *(const float4*)(p + 4);
            rb.f[2] = *(const float4*)(p + 8);
            rb.f[3] = *(const float4*)(p + 12);
        } else if constexpr (BFMT == 1) {
            const u16* ph = Bhp + (long long)(n0 + br) * ldb + k0 + bg * 16;
            const u16* pl = Blp + (long long)(n0 + br) * ldb + k0 + bg * 16;
            rb.h[0] = *(const u16x8*)(ph);
            rb.h[1] = *(const u16x8*)(ph + 8);
            rb.l[0] = *(const u16x8*)(pl);
            rb.l[1] = *(const u16x8*)(pl + 8);
        } else {
            int q0 = (k0 >> 1) + bg * 8;
            const float* p0 = Bfp + (long long)(n0 + br) * HWW + q0;
            const float* p1 = p0 + (long long)HWW * HWW;
            rb.f[0] = *(const float4*)(p0);
            rb.f[1] = *(const float4*)(p0 + 4);
            rb.f[2] = *(const float4*)(p1);
            rb.f[3] = *(const float4*)(p1 + 4);
        }
    };
    auto stageWrite = [&](char* sb, RegsA& ra, RegsB& rb) {
        *(u16x8*)(sb + ar * 64 + as0 * 16) = ra.h[0];
        *(u16x8*)(sb + ar * 64 + as1 * 16) = ra.h[1];
        *(u16x8*)(sb + 8192 + ar * 64 + as0 * 16) = ra.l[0];
        *(u16x8*)(sb + 8192 + ar * 64 + as1 * 16) = ra.l[1];
        if (bact) {
            char* sB = sb + 16384;
            if constexpr (BFMT == 1) {
                *(u16x8*)(sB + br * 64 + bs0 * 16) = rb.h[0];
                *(u16x8*)(sB + br * 64 + bs1 * 16) = rb.h[1];
                *(u16x8*)(sB + BNB + br * 64 + bs0 * 16) = rb.l[0];
                *(u16x8*)(sB + BNB + br * 64 + bs1 * 16) = rb.l[1];
            } else {
                float v[16];
                if constexpr (BFMT == 0) {
                    float vv[16] = {rb.f[0].x, rb.f[0].y, rb.f[0].z, rb.f[0].w,
                                    rb.f[1].x, rb.f[1].y, rb.f[1].z, rb.f[1].w,
                                    rb.f[2].x, rb.f[2].y, rb.f[2].z, rb.f[2].w,
                                    rb.f[3].x, rb.f[3].y, rb.f[3].z, rb.f[3].w};
                    #pragma unroll
                    for (int j = 0; j < 16; ++j) v[j] = vv[j];
                } else {
                    float vv[16] = {rb.f[0].x, rb.f[2].x, rb.f[0].y, rb.f[2].y,
                                    rb.f[0].z, rb.f[2].z, rb.f[0].w, rb.f[2].w,
                                    rb.f[1].x, rb.f[3].x, rb.f[1].y, rb.f[3].y,
                                    rb.f[1].z, rb.f[3].z, rb.f[1].w, rb.f[3].w};
                    #pragma unroll
                    for (int j = 0; j < 16; ++j) v[j] = vv[j];
                }
                u16x8 h0, h1, l0, l1;
                split16(v, h0, h1, l0, l1);
                *(u16x8*)(sB + br * 64 + bs0 * 16) = h0;
                *(u16x8*)(sB + br * 64 + bs1 * 16) = h1;
                *(u16x8*)(sB + BNB + br * 64 + bs0 * 16) = l0;
                *(u16x8*)(sB + BNB + br * 64 + bs1 * 16) = l1;
            }
        }
    };

    f32x4 acc[4][NJ];
    #pragma unroll
    for (int i = 0; i < 4; ++i)
        #pragma unroll
        for (int j = 0; j < NJ; ++j)
            acc[i][j] = (f32x4){0.f, 0.f, 0.f, 0.f};

    RegsA a0, a1;
    RegsB b0, b1;
    const int NIT = K >> 5;

    loadA(0, a0); loadB(0, b0);
    stageWrite(smem[0], a0, b0);
    loadA(32, a1); loadB(32, b1);
    asm volatile("s_waitcnt lgkmcnt(0)" ::: "memory");
    __builtin_amdgcn_s_barrier();

    auto step = [&](int it, char* sb, char* sn, RegsA& pa, RegsB& pb,
                    RegsA& qa, RegsB& qb) {
        bf16x8 fah[4], fal[4], fbh[NJ], fbl[NJ];
        #pragma unroll
        for (int i = 0; i < 4; ++i) {
            fah[i] = *(const bf16x8*)(sb + aoff + i * 1024);
            fal[i] = *(const bf16x8*)(sb + 8192 + aoff + i * 1024);
        }
        #pragma unroll
        for (int j = 0; j < NJ; ++j) {
            fbh[j] = *(const bf16x8*)(sb + 16384 + boff + j * 1024);
            fbl[j] = *(const bf16x8*)(sb + 16384 + BNB + boff + j * 1024);
        }
        if (it + 1 < NIT) stageWrite(sn, pa, pb);
        if (it + 2 < NIT) { loadA((it + 2) << 5, qa); loadB((it + 2) << 5, qb); }
        #pragma unroll
        for (int i = 0; i < 4; ++i)
            #pragma unroll
            for (int j = 0; j < NJ; ++j) {
                acc[i][j] = __builtin_amdgcn_mfma_f32_16x16x32_bf16(fal[i], fbh[j], acc[i][j], 0, 0, 0);
                acc[i][j] = __builtin_amdgcn_mfma_f32_16x16x32_bf16(fah[i], fbl[j], acc[i][j], 0, 0, 0);
                acc[i][j] = __builtin_amdgcn_mfma_f32_16x16x32_bf16(fah[i], fbh[j], acc[i][j], 0, 0, 0);
            }
        asm volatile("s_waitcnt lgkmcnt(0)" ::: "memory");
        __builtin_amdgcn_s_barrier();
    };

    for (int it = 0; it < NIT; it += 2) {
        step(it,     smem[0], smem[1], a1, b1, a0, b0);
        step(it + 1, smem[1], smem[0], a0, b0, a1, b1);
    }

    #pragma unroll
    for (int i = 0; i < 4; ++i) {
        #pragma unroll
        for (int r = 0; r < 4; ++r) {
            int row = m0 + wr * 64 + i * 16 + kq * 4 + r;
            float sc = 1.0f, bi = 0.0f;
            if (EPI == 1) { sc = gp[row] * BN_RSQRT; bi = bpb[row]; }
            #pragma unroll
            for (int j = 0; j < NJ; ++j) {
                int col = n0 + wc * (BN_ / 2) + j * 16 + rl;
                float v = acc[i][j][r];
                if constexpr (EPI == 0) {
                    ((float*)Cp + (long long)bz * cB)[(long long)row * ldc + col] = v;
                } else if constexpr (EPI == 1) {
                    v = fmaxf(fmaf(v, sc, bi), 0.0f);
                    ((float*)Cp + (long long)bz * cB)[(long long)row * ldc + col] = v;
                } else {
                    unsigned short hh, ll; split2(v, hh, ll);
                    ((u16*)Cp  + (long long)bz * cB)[(long long)row * ldc + col] = hh;
                    ((u16*)Cp2 + (long long)bz * cB)[(long long)row * ldc + col] = ll;
                    if constexpr (EPI == 2) {
                        ((u16*)Ct  + (long long)bz * cB)[(long long)col * ldct + row] = hh;
                        ((u16*)Ct2 + (long long)bz * cB)[(long long)col * ldct + row] = ll;
                    }
                }
            }
        }
    }
}

// ---------------------------------------------------------------------------
// Row L2-norm over C of Y[B][D][C] fp32 -> in-place split planes (lda=4096)
// ---------------------------------------------------------------------------
__global__ __launch_bounds__(256) void rownorm_split_k(float* __restrict__ Y) {
    int d = blockIdx.x, b = blockIdx.y, t = threadIdx.x;
    float* row = Y + ((long long)b * DD + d) * CC;
    float4 v0 = ((const float4*)row)[2 * t];
    float4 v1 = ((const float4*)row)[2 * t + 1];
    float s = v0.x * v0.x + v0.y * v0.y + v0.z * v0.z + v0.w * v0.w
            + v1.x * v1.x + v1.y * v1.y + v1.z * v1.z + v1.w * v1.w;
    for (int off = 32; off > 0; off >>= 1) s += __shfl_down(s, off, 64);
    __shared__ float wsum[4];
    __shared__ float ivs;
    int lane = t & 63, w = t >> 6;
    if (lane == 0) wsum[w] = s;
    __syncthreads();
    if (t == 0) ivs = 1.0f / fmaxf(sqrtf(wsum[0] + wsum[1] + wsum[2] + wsum[3]), 1e-12f);
    __syncthreads();
    float iv = ivs;
    float xs[8] = {v0.x * iv, v0.y * iv, v0.z * iv, v0.w * iv,
                   v1.x * iv, v1.y * iv, v1.z * iv, v1.w * iv};
    u16x8 h, l2;
    #pragma unroll
    for (int j = 0; j < 8; ++j) { unsigned short hh, ll; split2(xs[j], hh, ll); h[j] = hh; l2[j] = ll; }
    u16* hi = (u16*)row;
    *(u16x8*)(hi + t * 8) = h;
    *(u16x8*)(hi + CC + t * 8) = l2;
}

// ---------------------------------------------------------------------------
__global__ __launch_bounds__(256) void colnorm_k(const float* __restrict__ Yl,
                                                 float* __restrict__ rsc) {
    int b = blockIdx.y;
    int c = blockIdx.x * 256 + threadIdx.x;
    const float* base = Yl + (long long)b * DD * CC + c;
    float s = 0.0f;
    for (int d = 0; d < DD; ++d) { float v = base[(long long)d * CC]; s += v * v; }
    rsc[(long long)b * CC + c] = 1.0f / fmaxf(sqrtf(s), 1e-12f);
}

// ---------------------------------------------------------------------------
// transpose + column-scale + split: Yl[B][D][C] -> Ylt planes [B][C][D]
// ---------------------------------------------------------------------------
__global__ __launch_bounds__(256) void trans_split_k(const float* __restrict__ in,
                                                     const float* __restrict__ scale,
                                                     u16* __restrict__ hi, u16* __restrict__ lo) {
    __shared__ float tile[32][33];
    int s0 = blockIdx.x * 32, r0 = blockIdx.y * 32, b = blockIdx.z;
    const float* inb = in + (long long)b * DD * CC;
    int tx = threadIdx.x & 31, ty = threadIdx.x >> 5;
    for (int i = ty; i < 32; i += 8)
        tile[i][tx] = inb[(long long)(r0 + i) * CC + s0 + tx];
    __syncthreads();
    for (int i = ty; i < 32; i += 8) {
        float v = tile[tx][i] * scale[(long long)b * CC + s0 + i];
        unsigned short hh, ll; split2(v, hh, ll);
        long long o = (long long)b * DD * CC + (long long)(s0 + i) * DD + r0 + tx;
        hi[o] = hh; lo[o] = ll;
    }
}

// ---------------------------------------------------------------------------
__global__ __launch_bounds__(256) void latnorm_k(const float* __restrict__ G,
                                                 float* __restrict__ rs) {
    int i = blockIdx.x * 256 + threadIdx.x;
    int b = i >> 8, d = i & 255;
    float v = G[((long long)b * DD + d) * DD + d];
    rs[i] = 1.0f / fmaxf(sqrtf(v), 1e-12f);
}

// softmax over gram rows -> aff hi/lo planes
__global__ __launch_bounds__(256) void softmax_k(const float* __restrict__ G,
                                                 const float* __restrict__ rs,
                                                 u16* __restrict__ affHi,
                                                 u16* __restrict__ affLo) {
    int d = blockIdx.x, b = blockIdx.y;
    const float* row = G + ((long long)b * DD + d) * DD;
    const float* rsb = rs + (long long)b * DD;
    int t = threadIdx.x;
    float lg = row[t] * rsb[d] * rsb[t];

    float m = lg;
    for (int off = 32; off > 0; off >>= 1) m = fmaxf(m, __shfl_down(m, off, 64));
    __shared__ float wsm[4];
    __shared__ float bm, bs;
    int lane = t & 63, w = t >> 6;
    if (lane == 0) wsm[w] = m;
    __syncthreads();
    if (t == 0) bm = fmaxf(fmaxf(wsm[0], wsm[1]), fmaxf(wsm[2], wsm[3]));
    __syncthreads();
    float e = expf(lg - bm);
    float s = e;
    for (int off = 32; off > 0; off >>= 1) s += __shfl_down(s, off, 64);
    if (lane == 0) wsm[w] = s;
    __syncthreads();
    if (t == 0) bs = wsm[0] + wsm[1] + wsm[2] + wsm[3];
    __syncthreads();
    float v = e / bs;
    unsigned short hh, ll; split2(v, hh, ll);
    long long o = ((long long)b * DD + d) * DD + t;
    affHi[o] = hh; affLo[o] = ll;
}

// ---------------------------------------------------------------------------
extern "C" void kernel_launch(void* const* d_in, const int* in_sizes, int n_in,
                              void* d_out, int out_size, void* d_ws, size_t ws_size,
                              hipStream_t stream) {
    const float* v2l   = (const float*)d_in[0];
    const float* l2v   = (const float*)d_in[1];
    const float* w_v2l = (const float*)d_in[2];
    const float* g_v2l = (const float*)d_in[3];
    const float* b_v2l = (const float*)d_in[4];
    const float* w_l2v = (const float*)d_in[5];
    const float* g_l2v = (const float*)d_in[6];
    const float* b_l2v = (const float*)d_in[7];
    float* out = (float*)d_out;

    char* W = (char*)d_ws;
    float* Yv     = (float*)(W + 0);            // 32MB fp32 -> in-place planes
    float* Yl     = (float*)(W + 33554432);     // 32MB
    u16*   YltHi  = (u16*)(W + 67108864);       // 16MB
    u16*   YltLo  = (u16*)(W + 83886080);       // 16MB
    u16*   latHi  = (u16*)(W + 100663296);      //  8MB
    u16*   latLo  = (u16*)(W + 109051904);      //  8MB
    u16*   latTHi = (u16*)(W + 117440512);      //  8MB
    u16*   latTLo = (u16*)(W + 125829120);      //  8MB
    u16*   l2tHi  = (u16*)(W + 134217728);      //  8MB
    u16*   l2tLo  = (u16*)(W + 142606336);      //  8MB
    float* gram   = (float*)(W + 150994944);    //  4MB
    float* rs     = (float*)(W + 155189248);
    float* rsc    = (float*)(W + 155205632);
    u16*   affHi  = (u16*)(W + 155336704);      //  2MB
    u16*   affLo  = (u16*)(W + 157433856);      //  2MB
    u16*   WvHi   = (u16*)(W + 159531008);      //  512KB each
    u16*   WvLo   = WvHi + 262144;
    u16*   WlHi   = WvLo + 262144;
    u16*   WlLo   = WlHi + 262144;

    const long long sY   = (long long)DD * CC;     // 524288
    const long long sL   = (long long)DD * HWW;    // 262144
    const long long sG   = (long long)DD * DD;     // 65536
    const long long sX   = (long long)CC * HWW;    // 2097152
    const long long sYp  = (long long)DD * 4096;   // in-place plane stride

    // weights -> planes
    split_k<<<128, 256, 0, stream>>>(w_v2l, WvHi, WvLo, 32768);
    split_k<<<128, 256, 0, stream>>>(w_l2v, WlHi, WlLo, 32768);

    // G1+G2 fused (8-phase 256^2): Yv/Yl = relu(sc*(W . X^T)+b)  [D=256, C=2048]
    gemm8<0, 1, 1><<<dim3(CC / 256, 1, 32), 512, 0, stream>>>(
        WvHi, WvLo, WlHi, WlLo, 0, HWW,
        v2l, nullptr, l2v, nullptr, sX, HWW,
        Yv, Yl, sY, CC, HWW,
        g_v2l, b_v2l, g_l2v, b_l2v);

    rownorm_split_k<<<dim3(DD, BB), 256, 0, stream>>>(Yv);
    colnorm_k<<<dim3(CC / 256, BB), 256, 0, stream>>>(Yl, rsc);
    trans_split_k<<<dim3(CC / 32, DD / 32, BB), 256, 0, stream>>>(Yl, rsc, YltHi, YltLo);

    // G3: latent = Yvn . B3^T  [D,HW]; emits latent planes + latentT planes
    mfma_gemm<64, 1, 2, 2><<<dim3(HWW / 64, 2, BB), 256, 0, stream>>>(
        (const u16*)Yv, (const u16*)Yv + CC, sYp, 4096, v2l, nullptr, sX, HWW,
        latHi, latLo, latTHi, latTLo, sL, HWW, DD, CC, nullptr, nullptr);

    // gram = latent . latent^T  (plane MFMA, fp32 out)
    mfma_gemm<64, 1, 1, 0><<<dim3(4, 2, BB), 256, 0, stream>>>(
        latHi, latLo, sL, HWW, latHi, latLo, sL, HWW,
        gram, nullptr, nullptr, nullptr, sG, DD, 0, HWW, nullptr, nullptr);

    latnorm_k<<<dim3(BB * DD / 256), 256, 0, stream>>>(gram, rs);
    softmax_k<<<dim3(DD, BB), 256, 0, stream>>>(gram, rs, affHi, affLo);

    // lat2t = latentT . aff^T  [HW,D] -> planes (l2t)
    mfma_gemm<128, 1, 1, 3><<<dim3(2, HWW / 128, BB), 256, 0, stream>>>(
        latTHi, latTLo, sL, DD, affHi, affLo, sG, DD,
        l2tHi, l2tLo, nullptr, nullptr, sL, DD, 0, DD, nullptr, nullptr);

    // G6 (8-phase 256^2): out = Ylt . l2t^T  [C=2048, HW=1024]
    gemm8<1, 0, 0><<<dim3(HWW / 256, CC / 256, BB), 512, 0, stream>>>(
        YltHi, YltLo, nullptr, nullptr, sY, DD,
        l2tHi, l2tLo, nullptr, nullptr, sL, DD,
        out, nullptr, sX, HWW, DD,
        nullptr, nullptr, nullptr, nullptr);
}